// Round 2
// baseline (528.101 us; speedup 1.0000x reference)
//
#include <hip/hip_runtime.h>

#define DI 2048
#define DM 1024
#define DS 16
#define LEN 1024
#define NB 2
#define NROWS (NB * LEN)        // 2048
#define NPROJ (2 * DS + DI)     // 2080
#define NPROJ_PAD 2176
#define N_XZ (2 * DI)           // 4096

using bf16x8 = __attribute__((ext_vector_type(8))) short;
using f32x4  = __attribute__((ext_vector_type(4))) float;

__device__ __forceinline__ unsigned short f32_bf16(float f) {
  unsigned int u = __float_as_uint(f);
  u += 0x7fffu + ((u >> 16) & 1u);   // round-to-nearest-even
  return (unsigned short)(u >> 16);
}
__device__ __forceinline__ unsigned int packbf(float lo, float hi) {
  return (unsigned int)f32_bf16(lo) | ((unsigned int)f32_bf16(hi) << 16);
}

// ---------------- transpose + cast: W (K x N) f32 -> Wt (Npad x K) bf16 -----
__global__ __launch_bounds__(256)
void k_transpose_bf16(const float* __restrict__ W, unsigned short* __restrict__ Wt,
                      int K, int N) {
  __shared__ float tile[32][33];
  const int n0 = blockIdx.x * 32, k0 = blockIdx.y * 32;
  const int tx = threadIdx.x & 31;
  const int ty = threadIdx.x >> 5;   // 0..7
#pragma unroll
  for (int j = 0; j < 32; j += 8) {
    const int n = n0 + tx, k = k0 + ty + j;
    tile[ty + j][tx] = (n < N) ? W[(size_t)k * N + n] : 0.f;  // pad rows -> 0
  }
  __syncthreads();
#pragma unroll
  for (int j = 0; j < 32; j += 8)
    Wt[(size_t)(n0 + ty + j) * K + (k0 + tx)] = f32_bf16(tile[tx][ty + j]);
}

// ---------------- bf16 MFMA GEMM: C(MxN f32) = A(MxK f32) * Bt(NxK bf16)^T + bias
// 128x128 tile, 4 waves (2x2), each wave 64x64 = 4x4 fragments of 16x16x32.
// LDS rows padded to 40 bf16 (80B): frag ds_read_b128 pattern is bank-balanced.
__global__ __launch_bounds__(256)
void k_gemm(const float* __restrict__ A, int lda,
            const unsigned short* __restrict__ Bt, int ldb,
            const float* __restrict__ bias,
            float* __restrict__ C, int ldc,
            int K, int Nlog) {
  __shared__ __align__(16) unsigned short As[128 * 40];
  __shared__ __align__(16) unsigned short Bs[128 * 40];
  const int tid = threadIdx.x;
  const int m0 = blockIdx.y * 128;
  const int n0 = blockIdx.x * 128;
  const int lane = tid & 63;
  const int wid = tid >> 6;
  const int wr = (wid >> 1) * 64, wc = (wid & 1) * 64;
  const int g = lane >> 4, r = lane & 15;

  const int srow = tid >> 1;          // 0..127
  const int scol = (tid & 1) * 16;    // 0 or 16

  const float* Ap = A + (size_t)(m0 + srow) * lda + scol;
  const unsigned short* Bp = Bt + (size_t)(n0 + srow) * ldb + scol;
  unsigned short* Asw = &As[srow * 40 + scol];
  unsigned short* Bsw = &Bs[srow * 40 + scol];

  f32x4 acc[4][4] = {};

  for (int k0 = 0; k0 < K; k0 += 32) {
    const float4 a0 = *(const float4*)(Ap + k0);
    const float4 a1 = *(const float4*)(Ap + k0 + 4);
    const float4 a2 = *(const float4*)(Ap + k0 + 8);
    const float4 a3 = *(const float4*)(Ap + k0 + 12);
    const uint4 b0 = *(const uint4*)(Bp + k0);
    const uint4 b1 = *(const uint4*)(Bp + k0 + 8);
    const uint4 qa0 = make_uint4(packbf(a0.x, a0.y), packbf(a0.z, a0.w),
                                 packbf(a1.x, a1.y), packbf(a1.z, a1.w));
    const uint4 qa1 = make_uint4(packbf(a2.x, a2.y), packbf(a2.z, a2.w),
                                 packbf(a3.x, a3.y), packbf(a3.z, a3.w));
    *(uint4*)Asw = qa0;
    *(uint4*)(Asw + 8) = qa1;
    *(uint4*)Bsw = b0;
    *(uint4*)(Bsw + 8) = b1;
    __syncthreads();

    bf16x8 af[4], bfr[4];
#pragma unroll
    for (int i = 0; i < 4; ++i)
      af[i] = *(const bf16x8*)&As[(wr + i * 16 + r) * 40 + 8 * g];
#pragma unroll
    for (int j = 0; j < 4; ++j)
      bfr[j] = *(const bf16x8*)&Bs[(wc + j * 16 + r) * 40 + 8 * g];
#pragma unroll
    for (int i = 0; i < 4; ++i)
#pragma unroll
      for (int j = 0; j < 4; ++j)
        acc[i][j] = __builtin_amdgcn_mfma_f32_16x16x32_bf16(af[i], bfr[j], acc[i][j], 0, 0, 0);
    __syncthreads();
  }

#pragma unroll
  for (int i = 0; i < 4; ++i) {
    const int row = m0 + wr + i * 16 + 4 * g;  // C/D: row=(lane>>4)*4+reg
#pragma unroll
    for (int j = 0; j < 4; ++j) {
      const int col = n0 + wc + j * 16 + r;    // C/D: col=lane&15
      if (col < Nlog) {
        const float bv = bias[col];
#pragma unroll
        for (int q = 0; q < 4; ++q)
          C[(size_t)(row + q) * ldc + col] = acc[i][j][q] + bv;
      }
    }
  }
}

// ---------------- causal depthwise conv (k=4) + silu --------------------
__global__ __launch_bounds__(256)
void k_conv_silu(const float* __restrict__ xz, const float* __restrict__ cw,
                 const float* __restrict__ cb, float* __restrict__ xs) {
  const int idx = blockIdx.x * 256 + threadIdx.x;   // row*DI + d
  const int d = idx & (DI - 1);
  const int row = idx >> 11;          // b*LEN + l
  const int l = row & (LEN - 1);
  const float w0 = cw[d * 4], w1 = cw[d * 4 + 1], w2 = cw[d * 4 + 2], w3 = cw[d * 4 + 3];
  const float* p = xz + (size_t)row * N_XZ + d;     // xc = first DI cols of xz
  float acc = cb[d] + w3 * p[0];
  if (l >= 1) acc += w2 * p[-N_XZ];
  if (l >= 2) acc += w1 * p[-2 * N_XZ];
  if (l >= 3) acc += w0 * p[-3 * N_XZ];
  xs[idx] = acc / (1.f + expf(-acc));               // silu
}

// ---------------- dt = softplus(proj[:, :16] @ dt_proj_w + b) ------------
__global__ __launch_bounds__(256)
void k_dtproj(const float* __restrict__ proj, const float* __restrict__ w,
              const float* __restrict__ b, float* __restrict__ dt) {
  const int idx = blockIdx.x * 256 + threadIdx.x;
  const int d = idx & (DI - 1);
  const int row = idx >> 11;
  const float* p = proj + (size_t)row * NPROJ;
  float acc = b[d];
#pragma unroll
  for (int s = 0; s < DS; ++s) acc += p[s] * w[s * DI + d];
  dt[idx] = fmaxf(acc, 0.f) + log1pf(expf(-fabsf(acc)));  // stable softplus
}

// ---------------- selective scan + gating --------------------------------
// block = 16 d-channels x 16 states. Faithful to reference:
//   term[l] = exp(prefix[l-1]) * dt*Bp*xs ; h = cumsum(term) ; y = Cp*sum_s(h)+xs*D
// Once exp(prefix)==0 (f32 underflow, exactly as in the reference) for a whole
// 16-lane s-group, sum_s h is frozen -> switch to a parallel gating loop.
// NOTE: v aliases dt (dt[row,d] is read by the group before the s==0 lane's
// store in the same wave-synchronous iteration; never re-read afterwards).
__global__ __launch_bounds__(256)
void k_scan(const float* __restrict__ dt, const float* __restrict__ proj,
            const float* __restrict__ xs, const float* __restrict__ xz,
            const float* __restrict__ Alog, const float* __restrict__ Dp,
            float* __restrict__ v) {
  const int b = blockIdx.x >> 7;
  const int d0 = (blockIdx.x & 127) << 4;
  const int tid = threadIdx.x;
  const int s = tid & 15;
  const int d = d0 + (tid >> 4);
  const unsigned int gsh = (tid & 63) & 48;   // 16-lane group base within wave

  const float a = -expf(Alog[d * DS + s]);
  const float Dd = Dp[d];

  float P = 0.f, ep = 1.f, h = 0.f, hs_f = 0.f;
  const int rb = b * LEN;
  int l = 0;
  bool done = false;
  for (; l < LEN && !done; ++l) {
    const size_t row = (size_t)(rb + l);
    const float dtv = dt[row * DI + d];
    const float bp = proj[row * NPROJ + DS + s];
    const float xv = xs[row * DI + d];
    h += ep * (dtv * bp * xv);                 // ep = exp(prefix_shift[l])
    P += logf(expf(dtv * a) + 1e-8f);
    ep = expf(P);
    float hs = h;
    hs += __shfl_xor(hs, 1, 16);
    hs += __shfl_xor(hs, 2, 16);
    hs += __shfl_xor(hs, 4, 16);
    hs += __shfl_xor(hs, 8, 16);
    if (s == 0) {
      const float cp = proj[row * NPROJ + 2 * DS + d];
      const float z = xz[row * N_XZ + DI + d];
      const float y = cp * hs + xv * Dd;
      v[row * DI + d] = y * (z / (1.f + expf(-z)));
    }
    const unsigned long long bal = __ballot(ep == 0.f);
    if (((bal >> gsh) & 0xFFFFull) == 0xFFFFull) { hs_f = hs; done = true; }
  }
  // saturated tail: h-sum frozen, distribute timesteps over the 16 s-lanes
  for (int lb = l; lb < LEN; lb += 16) {
    const int ll = lb + s;
    if (ll < LEN) {
      const size_t row = (size_t)(rb + ll);
      const float cp = proj[row * NPROJ + 2 * DS + d];
      const float z = xz[row * N_XZ + DI + d];
      const float xv = xs[row * DI + d];
      v[row * DI + d] = (cp * hs_f + xv * Dd) * (z / (1.f + expf(-z)));
    }
  }
}

extern "C" void kernel_launch(void* const* d_in, const int* in_sizes, int n_in,
                              void* d_out, int out_size, void* d_ws, size_t ws_size,
                              hipStream_t stream) {
  const float* x     = (const float*)d_in[0];
  const float* w_in  = (const float*)d_in[1];
  const float* b_in  = (const float*)d_in[2];
  const float* cw    = (const float*)d_in[3];
  const float* cb    = (const float*)d_in[4];
  const float* w_xp  = (const float*)d_in[5];
  const float* b_xp  = (const float*)d_in[6];
  const float* w_dt  = (const float*)d_in[7];
  const float* b_dt  = (const float*)d_in[8];
  const float* Alog  = (const float*)d_in[9];
  const float* Dp    = (const float*)d_in[10];
  const float* w_out = (const float*)d_in[11];
  const float* b_out = (const float*)d_in[12];
  float* out = (float*)d_out;

  // workspace layout (bytes), total ~84.8 MB.
  // dtb/vb OVERLAYS w1t+w2t: w1t dead after gemm1, w2t dead after gemm2,
  // dtb first written by k_dtproj which runs after gemm2. w3t (needed by
  // gemm3) sits beyond dtb's 16,777,216-byte extent (17,301,504).
  char* ws = (char*)d_ws;
  unsigned short* w1t = (unsigned short*)(ws);              // 4096x1024 bf16 =  8,388,608
  unsigned short* w2t = (unsigned short*)(ws + 8388608);    // 2176x2048 bf16 =  8,912,896
  unsigned short* w3t = (unsigned short*)(ws + 17301504);   // 1024x2048 bf16 =  4,194,304
  float* xz   = (float*)(ws + 21495808);                    // 2048x4096 f32 = 33,554,432
  float* xsb  = (float*)(ws + 55050240);                    // 2048x2048 f32 = 16,777,216
  float* proj = (float*)(ws + 71827456);                    // 2048x2080 f32 = 17,039,360
  float* dtb  = (float*)(ws);                               // 2048x2048 f32 (overlay, see above)
  float* vb   = dtb;                                        // v aliases dt (see k_scan)

  const dim3 blk(256);
  // weight transpose + bf16 cast
  k_transpose_bf16<<<dim3(4096 / 32, 1024 / 32), blk, 0, stream>>>(w_in, w1t, 1024, 4096);
  k_transpose_bf16<<<dim3(NPROJ_PAD / 32, 2048 / 32), blk, 0, stream>>>(w_xp, w2t, 2048, NPROJ);
  k_transpose_bf16<<<dim3(1024 / 32, 2048 / 32), blk, 0, stream>>>(w_out, w3t, 2048, 1024);
  // xz = x @ in_proj_w + b
  k_gemm<<<dim3(4096 / 128, 2048 / 128), blk, 0, stream>>>(x, 1024, w1t, 1024, b_in, xz, 4096, 1024, 4096);
  // xs = silu(causal_dwconv(xc))
  k_conv_silu<<<dim3(NROWS * DI / 256), blk, 0, stream>>>(xz, cw, cb, xsb);
  // proj = xs @ x_proj_w + b
  k_gemm<<<dim3(NPROJ_PAD / 128, 2048 / 128), blk, 0, stream>>>(xsb, 2048, w2t, 2048, b_xp, proj, NPROJ, 2048, NPROJ);
  // dt = softplus(proj[:, :16] @ dt_proj_w + b)
  k_dtproj<<<dim3(NROWS * DI / 256), blk, 0, stream>>>(proj, w_dt, b_dt, dtb);
  // selective scan + gate -> v
  k_scan<<<dim3(NB * (DI / 16)), blk, 0, stream>>>(dtb, proj, xsb, xz, Alog, Dp, vb);
  // out = v @ out_proj_w + b
  k_gemm<<<dim3(1024 / 128, 2048 / 128), blk, 0, stream>>>(vb, 2048, w3t, 2048, b_out, out, 1024, 2048, 1024);
}

// Round 4
// 500.123 us; speedup vs baseline: 1.0559x; 1.0559x over previous
//
#include <hip/hip_runtime.h>

#define DI 2048
#define DM 1024
#define DS 16
#define LEN 1024
#define NB 2
#define NROWS (NB * LEN)        // 2048
#define NPROJ (2 * DS + DI)     // 2080
#define NPROJ_PAD 2176
#define N_XZ (2 * DI)           // 4096
#define NC 16                   // scan chunks
#define LC (LEN / NC)           // 64 rows per chunk

using bf16x8 = __attribute__((ext_vector_type(8))) short;
using f32x4  = __attribute__((ext_vector_type(4))) float;

__device__ __forceinline__ unsigned short f32_bf16(float f) {
  unsigned int u = __float_as_uint(f);
  u += 0x7fffu + ((u >> 16) & 1u);   // round-to-nearest-even
  return (unsigned short)(u >> 16);
}
__device__ __forceinline__ unsigned int packbf(float lo, float hi) {
  return (unsigned int)f32_bf16(lo) | ((unsigned int)f32_bf16(hi) << 16);
}

// ---------------- transpose + cast: W (K x N) f32 -> Wt (Npad x K) bf16 -----
__global__ __launch_bounds__(256)
void k_transpose_bf16(const float* __restrict__ W, unsigned short* __restrict__ Wt,
                      int K, int N) {
  __shared__ float tile[32][33];
  const int n0 = blockIdx.x * 32, k0 = blockIdx.y * 32;
  const int tx = threadIdx.x & 31;
  const int ty = threadIdx.x >> 5;   // 0..7
#pragma unroll
  for (int j = 0; j < 32; j += 8) {
    const int n = n0 + tx, k = k0 + ty + j;
    tile[ty + j][tx] = (n < N) ? W[(size_t)k * N + n] : 0.f;  // pad rows -> 0
  }
  __syncthreads();
#pragma unroll
  for (int j = 0; j < 32; j += 8)
    Wt[(size_t)(n0 + ty + j) * K + (k0 + tx)] = f32_bf16(tile[tx][ty + j]);
}

// ---------------- bf16 MFMA GEMM (round-2 PASSING version, unchanged) -------
// C(MxN f32) = A(MxK f32) * Bt(NxK bf16)^T + bias. 128x128 tile, 4 waves.
__global__ __launch_bounds__(256)
void k_gemm(const float* __restrict__ A, int lda,
            const unsigned short* __restrict__ Bt, int ldb,
            const float* __restrict__ bias,
            float* __restrict__ C, int ldc,
            int K, int Nlog) {
  __shared__ __align__(16) unsigned short As[128 * 40];
  __shared__ __align__(16) unsigned short Bs[128 * 40];
  const int tid = threadIdx.x;
  const int m0 = blockIdx.y * 128;
  const int n0 = blockIdx.x * 128;
  const int lane = tid & 63;
  const int wid = tid >> 6;
  const int wr = (wid >> 1) * 64, wc = (wid & 1) * 64;
  const int g = lane >> 4, r = lane & 15;

  const int srow = tid >> 1;          // 0..127
  const int scol = (tid & 1) * 16;    // 0 or 16

  const float* Ap = A + (size_t)(m0 + srow) * lda + scol;
  const unsigned short* Bp = Bt + (size_t)(n0 + srow) * ldb + scol;
  unsigned short* Asw = &As[srow * 40 + scol];
  unsigned short* Bsw = &Bs[srow * 40 + scol];

  f32x4 acc[4][4] = {};

  for (int k0 = 0; k0 < K; k0 += 32) {
    const float4 a0 = *(const float4*)(Ap + k0);
    const float4 a1 = *(const float4*)(Ap + k0 + 4);
    const float4 a2 = *(const float4*)(Ap + k0 + 8);
    const float4 a3 = *(const float4*)(Ap + k0 + 12);
    const uint4 b0 = *(const uint4*)(Bp + k0);
    const uint4 b1 = *(const uint4*)(Bp + k0 + 8);
    const uint4 qa0 = make_uint4(packbf(a0.x, a0.y), packbf(a0.z, a0.w),
                                 packbf(a1.x, a1.y), packbf(a1.z, a1.w));
    const uint4 qa1 = make_uint4(packbf(a2.x, a2.y), packbf(a2.z, a2.w),
                                 packbf(a3.x, a3.y), packbf(a3.z, a3.w));
    *(uint4*)Asw = qa0;
    *(uint4*)(Asw + 8) = qa1;
    *(uint4*)Bsw = b0;
    *(uint4*)(Bsw + 8) = b1;
    __syncthreads();

    bf16x8 af[4], bfr[4];
#pragma unroll
    for (int i = 0; i < 4; ++i)
      af[i] = *(const bf16x8*)&As[(wr + i * 16 + r) * 40 + 8 * g];
#pragma unroll
    for (int j = 0; j < 4; ++j)
      bfr[j] = *(const bf16x8*)&Bs[(wc + j * 16 + r) * 40 + 8 * g];
#pragma unroll
    for (int i = 0; i < 4; ++i)
#pragma unroll
      for (int j = 0; j < 4; ++j)
        acc[i][j] = __builtin_amdgcn_mfma_f32_16x16x32_bf16(af[i], bfr[j], acc[i][j], 0, 0, 0);
    __syncthreads();
  }

#pragma unroll
  for (int i = 0; i < 4; ++i) {
    const int row = m0 + wr + i * 16 + 4 * g;  // C/D: row=(lane>>4)*4+reg
#pragma unroll
    for (int j = 0; j < 4; ++j) {
      const int col = n0 + wc + j * 16 + r;    // C/D: col=lane&15
      if (col < Nlog) {
        const float bv = bias[col];
#pragma unroll
        for (int q = 0; q < 4; ++q)
          C[(size_t)(row + q) * ldc + col] = acc[i][j][q] + bv;
      }
    }
  }
}

// ---------------- causal depthwise conv (k=4) + silu --------------------
__global__ __launch_bounds__(256)
void k_conv_silu(const float* __restrict__ xz, const float* __restrict__ cw,
                 const float* __restrict__ cb, float* __restrict__ xs) {
  const int idx = blockIdx.x * 256 + threadIdx.x;   // row*DI + d
  const int d = idx & (DI - 1);
  const int row = idx >> 11;          // b*LEN + l
  const int l = row & (LEN - 1);
  const float w0 = cw[d * 4], w1 = cw[d * 4 + 1], w2 = cw[d * 4 + 2], w3 = cw[d * 4 + 3];
  const float* p = xz + (size_t)row * N_XZ + d;     // xc = first DI cols of xz
  float acc = cb[d] + w3 * p[0];
  if (l >= 1) acc += w2 * p[-N_XZ];
  if (l >= 2) acc += w1 * p[-2 * N_XZ];
  if (l >= 3) acc += w0 * p[-3 * N_XZ];
  xs[idx] = acc / (1.f + expf(-acc));               // silu
}

// ---------------- dt = softplus(proj[:, :16] @ dt_proj_w + b) ------------
__global__ __launch_bounds__(256)
void k_dtproj(const float* __restrict__ proj, const float* __restrict__ w,
              const float* __restrict__ b, float* __restrict__ dt) {
  const int idx = blockIdx.x * 256 + threadIdx.x;
  const int d = idx & (DI - 1);
  const int row = idx >> 11;
  const float* p = proj + (size_t)row * NPROJ;
  float acc = b[d];
#pragma unroll
  for (int s = 0; s < DS; ++s) acc += p[s] * w[s * DI + d];
  dt[idx] = fmaxf(acc, 0.f) + log1pf(expf(-fabsf(acc)));  // stable softplus
}

// ---------------- selective scan: 3-phase chunk-parallel --------------------
// Per (b,d,s): e_j = prod_{i<j} (exp(dt_i*a_s)+1e-8)  (== exp(cumsum log) of
// the reference, carried multiplicatively); h_l = sum_{j<=l} e_j*dt_j*B_j*xs_j.
// Phase A: per 64-row chunk, chunk-product E_c and local weighted sum L_c.
// Phase B: exclusive scan over the 16 chunks -> chunk-start scale & H.
// Phase C: replay chunk with global scale, s-reduce via shfl, gate, store.
#define SIDX(b, c, d, s) ((((size_t)(b) * NC + (c)) << 15) + ((d) << 4) + (s))

__global__ __launch_bounds__(256)
void k_scanA(const float* __restrict__ dt, const float* __restrict__ proj,
             const float* __restrict__ xs, const float* __restrict__ Alog,
             float* __restrict__ Ebuf, float* __restrict__ Lbuf) {
  const int bx = blockIdx.x;
  const int dblk = bx & 127, c = (bx >> 7) & (NC - 1), b = bx >> 11;
  const int s = threadIdx.x & 15, d = dblk * 16 + (threadIdx.x >> 4);
  const float a = -expf(Alog[d * DS + s]);
  const int row0 = b * LEN + c * LC;
  float e = 1.f, Lsum = 0.f;
#pragma unroll 8
  for (int j = 0; j < LC; ++j) {
    const size_t row = (size_t)(row0 + j);
    const float dtv = dt[row * DI + d];
    const float xv = xs[row * DI + d];
    const float bp = proj[row * NPROJ + DS + s];
    Lsum += e * (dtv * bp * xv);
    e *= __expf(dtv * a) + 1e-8f;
  }
  const size_t idx = SIDX(b, c, d, s);
  Ebuf[idx] = e;
  Lbuf[idx] = Lsum;
}

__global__ __launch_bounds__(256)
void k_scanB(float* __restrict__ Ebuf, float* __restrict__ Lbuf) {
  const int gid = blockIdx.x * 256 + threadIdx.x;   // (b,d,s)
  const int s = gid & 15, d = (gid >> 4) & (DI - 1), b = gid >> 15;
  float scale = 1.f, H = 0.f;
#pragma unroll
  for (int c = 0; c < NC; ++c) {
    const size_t idx = SIDX(b, c, d, s);
    const float E = Ebuf[idx], Ls = Lbuf[idx];
    Ebuf[idx] = scale;                              // chunk-start scale
    Lbuf[idx] = H;                                  // chunk-start H
    H += scale * Ls;
    scale *= E;
  }
}

__global__ __launch_bounds__(256)
void k_scanC(const float* __restrict__ dt, const float* __restrict__ proj,
             const float* __restrict__ xs, const float* __restrict__ xz,
             const float* __restrict__ Alog, const float* __restrict__ Dp,
             const float* __restrict__ Ebuf, const float* __restrict__ Lbuf,
             float* __restrict__ v) {
  const int bx = blockIdx.x;
  const int dblk = bx & 127, c = (bx >> 7) & (NC - 1), b = bx >> 11;
  const int s = threadIdx.x & 15, d = dblk * 16 + (threadIdx.x >> 4);
  const float a = -expf(Alog[d * DS + s]);
  const float Dd = Dp[d];
  const size_t idx = SIDX(b, c, d, s);
  float e = Ebuf[idx];                              // global scale at chunk start
  float h = Lbuf[idx];                              // H at chunk start
  const int row0 = b * LEN + c * LC;
#pragma unroll 4
  for (int j = 0; j < LC; ++j) {
    const size_t row = (size_t)(row0 + j);
    const float dtv = dt[row * DI + d];             // read BEFORE v-store (alias)
    const float xv = xs[row * DI + d];
    const float bp = proj[row * NPROJ + DS + s];
    h += e * (dtv * bp * xv);
    float hs = h;
    hs += __shfl_xor(hs, 1, 16);
    hs += __shfl_xor(hs, 2, 16);
    hs += __shfl_xor(hs, 4, 16);
    hs += __shfl_xor(hs, 8, 16);
    if (s == 0) {
      const float cp = proj[row * NPROJ + 2 * DS + d];
      const float z = xz[row * N_XZ + DI + d];
      const float y = cp * hs + xv * Dd;
      v[row * DI + d] = y * (z / (1.f + __expf(-z)));
    }
    e *= __expf(dtv * a) + 1e-8f;
  }
}

extern "C" void kernel_launch(void* const* d_in, const int* in_sizes, int n_in,
                              void* d_out, int out_size, void* d_ws, size_t ws_size,
                              hipStream_t stream) {
  const float* x     = (const float*)d_in[0];
  const float* w_in  = (const float*)d_in[1];
  const float* b_in  = (const float*)d_in[2];
  const float* cw    = (const float*)d_in[3];
  const float* cb    = (const float*)d_in[4];
  const float* w_xp  = (const float*)d_in[5];
  const float* b_xp  = (const float*)d_in[6];
  const float* w_dt  = (const float*)d_in[7];
  const float* b_dt  = (const float*)d_in[8];
  const float* Alog  = (const float*)d_in[9];
  const float* Dp    = (const float*)d_in[10];
  const float* w_out = (const float*)d_in[11];
  const float* b_out = (const float*)d_in[12];
  float* out = (float*)d_out;

  // workspace layout: IDENTICAL to the round-2 passing layout (max 88,866,816 B).
  // dtb overlays w1t+w2t (dead after gemm2); v aliases dt (wave-sync safe);
  // Ebuf/Hbuf live in d_out (8 MB; dead until gemm3 overwrites it).
  char* ws = (char*)d_ws;
  unsigned short* w1t = (unsigned short*)(ws);              // 4096x1024 bf16 =  8,388,608
  unsigned short* w2t = (unsigned short*)(ws + 8388608);    // 2176x2048 bf16 =  8,912,896
  unsigned short* w3t = (unsigned short*)(ws + 17301504);   // 1024x2048 bf16 =  4,194,304
  float* xz   = (float*)(ws + 21495808);                    // 2048x4096 f32 = 33,554,432
  float* xsb  = (float*)(ws + 55050240);                    // 2048x2048 f32 = 16,777,216
  float* proj = (float*)(ws + 71827456);                    // 2048x2080 f32 = 17,039,360
  float* dtb  = (float*)(ws);                               // 2048x2048 f32 (overlay)
  float* vb   = dtb;                                        // v aliases dt (see k_scanC)
  float* Ebuf = out;                                        // 1,048,576 f32 (in d_out)
  float* Hbuf = out + 1048576;                              // 1,048,576 f32 (in d_out)

  const dim3 blk(256);
  // weight transpose + bf16 cast
  k_transpose_bf16<<<dim3(4096 / 32, 1024 / 32), blk, 0, stream>>>(w_in, w1t, 1024, 4096);
  k_transpose_bf16<<<dim3(NPROJ_PAD / 32, 2048 / 32), blk, 0, stream>>>(w_xp, w2t, 2048, NPROJ);
  k_transpose_bf16<<<dim3(1024 / 32, 2048 / 32), blk, 0, stream>>>(w_out, w3t, 2048, 1024);
  // xz = x @ in_proj_w + b
  k_gemm<<<dim3(4096 / 128, 2048 / 128), blk, 0, stream>>>(x, 1024, w1t, 1024, b_in, xz, 4096, 1024, 4096);
  // xs = silu(causal_dwconv(xc))
  k_conv_silu<<<dim3(NROWS * DI / 256), blk, 0, stream>>>(xz, cw, cb, xsb);
  // proj = xs @ x_proj_w + b
  k_gemm<<<dim3(NPROJ_PAD / 128, 2048 / 128), blk, 0, stream>>>(xsb, 2048, w2t, 2048, b_xp, proj, NPROJ, 2048, NPROJ);
  // dt = softplus(proj[:, :16] @ dt_proj_w + b)
  k_dtproj<<<dim3(NROWS * DI / 256), blk, 0, stream>>>(proj, w_dt, b_dt, dtb);
  // selective scan (3-phase chunk-parallel) + gate -> v
  k_scanA<<<dim3(NB * NC * 128), blk, 0, stream>>>(dtb, proj, xsb, Alog, Ebuf, Hbuf);
  k_scanB<<<dim3(NB * DI * DS / 256), blk, 0, stream>>>(Ebuf, Hbuf);
  k_scanC<<<dim3(NB * NC * 128), blk, 0, stream>>>(dtb, proj, xsb, xz, Alog, Dp, Ebuf, Hbuf, vb);
  // out = v @ out_proj_w + b
  k_gemm<<<dim3(1024 / 128, 2048 / 128), blk, 0, stream>>>(vb, 2048, w3t, 2048, b_out, out, 1024, 2048, 1024);
}

// Round 6
// 461.529 us; speedup vs baseline: 1.1442x; 1.0836x over previous
//
#include <hip/hip_runtime.h>

#define DI 2048
#define DM 1024
#define DS 16
#define LEN 1024
#define NB 2
#define NROWS (NB * LEN)        // 2048
#define NPROJ (2 * DS + DI)     // 2080
#define NPROJ_PAD 2176
#define N_XZ (2 * DI)           // 4096
#define CH_R 64                 // rows per scan chunk
#define NCH (LEN / CH_R)        // 16 chunks per batch
#define TOTCH (NB * NCH)        // 32 chunks total

using bf16x8 = __attribute__((ext_vector_type(8))) short;
using f32x4  = __attribute__((ext_vector_type(4))) float;

__device__ __forceinline__ unsigned short f32_bf16(float f) {
  unsigned int u = __float_as_uint(f);
  u += 0x7fffu + ((u >> 16) & 1u);   // round-to-nearest-even
  return (unsigned short)(u >> 16);
}
__device__ __forceinline__ unsigned int packbf(float lo, float hi) {
  return (unsigned int)f32_bf16(lo) | ((unsigned int)f32_bf16(hi) << 16);
}

// ---------------- transpose + cast: W (K x N) f32 -> Wt (Npad x K) bf16 -----
__global__ __launch_bounds__(256)
void k_transpose_bf16(const float* __restrict__ W, unsigned short* __restrict__ Wt,
                      int K, int N) {
  __shared__ float tile[32][33];
  const int n0 = blockIdx.x * 32, k0 = blockIdx.y * 32;
  const int tx = threadIdx.x & 31;
  const int ty = threadIdx.x >> 5;
#pragma unroll
  for (int j = 0; j < 32; j += 8) {
    const int n = n0 + tx, k = k0 + ty + j;
    tile[ty + j][tx] = (n < N) ? W[(size_t)k * N + n] : 0.f;  // pad rows -> 0
  }
  __syncthreads();
#pragma unroll
  for (int j = 0; j < 32; j += 8)
    Wt[(size_t)(n0 + ty + j) * K + (k0 + tx)] = f32_bf16(tile[tx][ty + j]);
}

// ---------------- f32-A MFMA GEMM (round-2/4 PASSING version, unchanged) ----
__global__ __launch_bounds__(256)
void k_gemm(const float* __restrict__ A, int lda,
            const unsigned short* __restrict__ Bt, int ldb,
            const float* __restrict__ bias,
            float* __restrict__ C, int ldc,
            int K, int Nlog) {
  __shared__ __align__(16) unsigned short As[128 * 40];
  __shared__ __align__(16) unsigned short Bs[128 * 40];
  const int tid = threadIdx.x;
  const int m0 = blockIdx.y * 128;
  const int n0 = blockIdx.x * 128;
  const int lane = tid & 63;
  const int wid = tid >> 6;
  const int wr = (wid >> 1) * 64, wc = (wid & 1) * 64;
  const int g = lane >> 4, r = lane & 15;

  const int srow = tid >> 1;
  const int scol = (tid & 1) * 16;

  const float* Ap = A + (size_t)(m0 + srow) * lda + scol;
  const unsigned short* Bp = Bt + (size_t)(n0 + srow) * ldb + scol;
  unsigned short* Asw = &As[srow * 40 + scol];
  unsigned short* Bsw = &Bs[srow * 40 + scol];

  f32x4 acc[4][4] = {};

  for (int k0 = 0; k0 < K; k0 += 32) {
    const float4 a0 = *(const float4*)(Ap + k0);
    const float4 a1 = *(const float4*)(Ap + k0 + 4);
    const float4 a2 = *(const float4*)(Ap + k0 + 8);
    const float4 a3 = *(const float4*)(Ap + k0 + 12);
    const uint4 b0 = *(const uint4*)(Bp + k0);
    const uint4 b1 = *(const uint4*)(Bp + k0 + 8);
    const uint4 qa0 = make_uint4(packbf(a0.x, a0.y), packbf(a0.z, a0.w),
                                 packbf(a1.x, a1.y), packbf(a1.z, a1.w));
    const uint4 qa1 = make_uint4(packbf(a2.x, a2.y), packbf(a2.z, a2.w),
                                 packbf(a3.x, a3.y), packbf(a3.z, a3.w));
    *(uint4*)Asw = qa0;
    *(uint4*)(Asw + 8) = qa1;
    *(uint4*)Bsw = b0;
    *(uint4*)(Bsw + 8) = b1;
    __syncthreads();

    bf16x8 af[4], bfr[4];
#pragma unroll
    for (int i = 0; i < 4; ++i)
      af[i] = *(const bf16x8*)&As[(wr + i * 16 + r) * 40 + 8 * g];
#pragma unroll
    for (int j = 0; j < 4; ++j)
      bfr[j] = *(const bf16x8*)&Bs[(wc + j * 16 + r) * 40 + 8 * g];
#pragma unroll
    for (int i = 0; i < 4; ++i)
#pragma unroll
      for (int j = 0; j < 4; ++j)
        acc[i][j] = __builtin_amdgcn_mfma_f32_16x16x32_bf16(af[i], bfr[j], acc[i][j], 0, 0, 0);
    __syncthreads();
  }

#pragma unroll
  for (int i = 0; i < 4; ++i) {
    const int row = m0 + wr + i * 16 + 4 * g;  // C/D: row=(lane>>4)*4+reg
#pragma unroll
    for (int j = 0; j < 4; ++j) {
      const int col = n0 + wc + j * 16 + r;    // C/D: col=lane&15
      if (col < Nlog) {
        const float bv = bias[col];
#pragma unroll
        for (int q = 0; q < 4; ++q)
          C[(size_t)(row + q) * ldc + col] = acc[i][j][q] + bv;
      }
    }
  }
}

// ---------------- causal depthwise conv (k=4) + silu (round-4, unchanged) ---
__global__ __launch_bounds__(256)
void k_conv_silu(const float* __restrict__ xz, const float* __restrict__ cw,
                 const float* __restrict__ cb, float* __restrict__ xs) {
  const int idx = blockIdx.x * 256 + threadIdx.x;   // row*DI + d
  const int d = idx & (DI - 1);
  const int row = idx >> 11;
  const int l = row & (LEN - 1);
  const float w0 = cw[d * 4], w1 = cw[d * 4 + 1], w2 = cw[d * 4 + 2], w3 = cw[d * 4 + 3];
  const float* p = xz + (size_t)row * N_XZ + d;     // xc = first DI cols of xz
  float acc = cb[d] + w3 * p[0];
  if (l >= 1) acc += w2 * p[-N_XZ];
  if (l >= 2) acc += w1 * p[-2 * N_XZ];
  if (l >= 3) acc += w0 * p[-3 * N_XZ];
  xs[idx] = acc / (1.f + expf(-acc));               // silu
}

// ---------------- dt = softplus(proj[:, :16] @ dt_proj_w + b) (unchanged) ---
__global__ __launch_bounds__(256)
void k_dtproj(const float* __restrict__ proj, const float* __restrict__ w,
              const float* __restrict__ b, float* __restrict__ dt) {
  const int idx = blockIdx.x * 256 + threadIdx.x;
  const int d = idx & (DI - 1);
  const int row = idx >> 11;
  const float* p = proj + (size_t)row * NPROJ;
  float acc = b[d];
#pragma unroll
  for (int s = 0; s < DS; ++s) acc += p[s] * w[s * DI + d];
  dt[idx] = fmaxf(acc, 0.f) + log1pf(expf(-fabsf(acc)));  // stable softplus
}

// ---------------- selective scan: chunk-parallel, s-in-registers ------------
// Round-4 PASSING algebra (multiplicative decay carry, exclusive chunk scan),
// re-tiled: thread = (chunk of 64 rows, d); 16 states in registers -> no
// shuffles, no masked gate block. Buffers: (chunkg,d,s) -> ((chunkg*DI+d)*16+s,
// 1,048,576 floats each (4 MB), living in d_out like round 4.
__global__ __launch_bounds__(256)
void k_scanA(const float* __restrict__ dt, const float* __restrict__ proj,
             const float* __restrict__ xs, const float* __restrict__ Alog,
             float* __restrict__ Ebuf, float* __restrict__ Lbuf) {
  __shared__ float bp_lds[CH_R][DS];                // 4 KB
  const int bx = blockIdx.x;                        // 0..255
  const int chunkg = bx >> 3;                       // 0..31
  const int d = (bx & 7) * 256 + threadIdx.x;       // 0..2047
  const int b = chunkg >> 4, c = chunkg & (NCH - 1);
  const int row0 = b * LEN + c * CH_R;
#pragma unroll
  for (int i = 0; i < 4; ++i) {                     // stage 64x16 B-rows
    const int e0 = threadIdx.x + i * 256;
    bp_lds[e0 >> 4][e0 & 15] = proj[(size_t)(row0 + (e0 >> 4)) * NPROJ + DS + (e0 & 15)];
  }
  __syncthreads();

  float a[DS], e[DS], L[DS];
#pragma unroll
  for (int s = 0; s < DS; ++s) {
    a[s] = -expf(Alog[d * DS + s]);
    e[s] = 1.f; L[s] = 0.f;
  }
#pragma unroll 4
  for (int j = 0; j < CH_R; ++j) {
    const size_t row = (size_t)(row0 + j);
    const float dtv = dt[row * DI + d];
    const float xv = xs[row * DI + d];
    const float u = dtv * xv;
#pragma unroll
    for (int q = 0; q < 4; ++q) {
      const float4 bq = *(const float4*)&bp_lds[j][q * 4];
      L[q * 4 + 0] += e[q * 4 + 0] * (u * bq.x);
      L[q * 4 + 1] += e[q * 4 + 1] * (u * bq.y);
      L[q * 4 + 2] += e[q * 4 + 2] * (u * bq.z);
      L[q * 4 + 3] += e[q * 4 + 3] * (u * bq.w);
    }
#pragma unroll
    for (int s = 0; s < DS; ++s)
      e[s] *= __expf(dtv * a[s]) + 1e-8f;
  }
  const size_t base = ((size_t)chunkg * DI + d) * DS;
#pragma unroll
  for (int q = 0; q < 4; ++q) {
    *(float4*)&Ebuf[base + q * 4] = make_float4(e[q*4], e[q*4+1], e[q*4+2], e[q*4+3]);
    *(float4*)&Lbuf[base + q * 4] = make_float4(L[q*4], L[q*4+1], L[q*4+2], L[q*4+3]);
  }
}

__global__ __launch_bounds__(256)
void k_scanB(float* __restrict__ Ebuf, float* __restrict__ Lbuf) {
  const int gid = blockIdx.x * 256 + threadIdx.x;   // b*32768 + d*16 + s
  const int s = gid & 15, d = (gid >> 4) & (DI - 1), b = gid >> 15;
  float scale = 1.f, H = 0.f;
#pragma unroll
  for (int c = 0; c < NCH; ++c) {
    const size_t idx = (((size_t)(b * NCH + c) * DI + d) << 4) + s;
    const float E = Ebuf[idx], Ls = Lbuf[idx];
    Ebuf[idx] = scale;                              // chunk-start scale
    Lbuf[idx] = H;                                  // chunk-start H
    H += scale * Ls;
    scale *= E;
  }
}

// dt and v ALIAS (same buffer): intentionally NOT __restrict__ so the
// compiler preserves per-address load-before-store order.
__global__ __launch_bounds__(256)
void k_scanC(const float* dt, const float* __restrict__ proj,
             const float* __restrict__ xs, const float* __restrict__ xz,
             const float* __restrict__ Alog, const float* __restrict__ Dp,
             const float* __restrict__ Ebuf, const float* __restrict__ Lbuf,
             float* v) {
  __shared__ float bp_lds[CH_R][DS];
  const int bx = blockIdx.x;
  const int chunkg = bx >> 3;
  const int d = (bx & 7) * 256 + threadIdx.x;
  const int b = chunkg >> 4, c = chunkg & (NCH - 1);
  const int row0 = b * LEN + c * CH_R;
#pragma unroll
  for (int i = 0; i < 4; ++i) {
    const int e0 = threadIdx.x + i * 256;
    bp_lds[e0 >> 4][e0 & 15] = proj[(size_t)(row0 + (e0 >> 4)) * NPROJ + DS + (e0 & 15)];
  }
  __syncthreads();

  const float Dd = Dp[d];
  float a[DS], e[DS], h[DS];
  const size_t base = ((size_t)chunkg * DI + d) * DS;
#pragma unroll
  for (int q = 0; q < 4; ++q) {
    const float4 ev = *(const float4*)&Ebuf[base + q * 4];
    const float4 hv = *(const float4*)&Lbuf[base + q * 4];
    e[q*4] = ev.x; e[q*4+1] = ev.y; e[q*4+2] = ev.z; e[q*4+3] = ev.w;
    h[q*4] = hv.x; h[q*4+1] = hv.y; h[q*4+2] = hv.z; h[q*4+3] = hv.w;
  }
#pragma unroll
  for (int s = 0; s < DS; ++s)
    a[s] = -expf(Alog[d * DS + s]);

#pragma unroll 4
  for (int j = 0; j < CH_R; ++j) {
    const size_t row = (size_t)(row0 + j);
    const float dtv = dt[row * DI + d];             // read BEFORE v-store (alias)
    const float xv = xs[row * DI + d];
    const float u = dtv * xv;
#pragma unroll
    for (int q = 0; q < 4; ++q) {
      const float4 bq = *(const float4*)&bp_lds[j][q * 4];
      h[q * 4 + 0] += e[q * 4 + 0] * (u * bq.x);
      h[q * 4 + 1] += e[q * 4 + 1] * (u * bq.y);
      h[q * 4 + 2] += e[q * 4 + 2] * (u * bq.z);
      h[q * 4 + 3] += e[q * 4 + 3] * (u * bq.w);
    }
    float hs = 0.f;
#pragma unroll
    for (int s = 0; s < DS; ++s) hs += h[s];
    const float cp = proj[row * NPROJ + 2 * DS + d];
    const float z = xz[row * N_XZ + DI + d];
    const float y = cp * hs + xv * Dd;
    v[row * DI + d] = y * (z / (1.f + __expf(-z)));
#pragma unroll
    for (int s = 0; s < DS; ++s)
      e[s] *= __expf(dtv * a[s]) + 1e-8f;
  }
}

extern "C" void kernel_launch(void* const* d_in, const int* in_sizes, int n_in,
                              void* d_out, int out_size, void* d_ws, size_t ws_size,
                              hipStream_t stream) {
  const float* x     = (const float*)d_in[0];
  const float* w_in  = (const float*)d_in[1];
  const float* b_in  = (const float*)d_in[2];
  const float* cw    = (const float*)d_in[3];
  const float* cb    = (const float*)d_in[4];
  const float* w_xp  = (const float*)d_in[5];
  const float* b_xp  = (const float*)d_in[6];
  const float* w_dt  = (const float*)d_in[7];
  const float* b_dt  = (const float*)d_in[8];
  const float* Alog  = (const float*)d_in[9];
  const float* Dp    = (const float*)d_in[10];
  const float* w_out = (const float*)d_in[11];
  const float* b_out = (const float*)d_in[12];
  float* out = (float*)d_out;

  // workspace layout: IDENTICAL to the round-4 passing layout (max 88,866,816 B).
  // dtb overlays w1t+w2t (dead after gemm2); v aliases dt (per-thread
  // read-then-write, non-restrict in k_scanC); Ebuf/Hbuf in d_out (2x4 MB,
  // dead until gemm3 overwrites d_out).
  char* ws = (char*)d_ws;
  unsigned short* w1t = (unsigned short*)(ws);              // 4096x1024 bf16 =  8,388,608
  unsigned short* w2t = (unsigned short*)(ws + 8388608);    // 2176x2048 bf16 =  8,912,896
  unsigned short* w3t = (unsigned short*)(ws + 17301504);   // 1024x2048 bf16 =  4,194,304
  float* xz   = (float*)(ws + 21495808);                    // 2048x4096 f32 = 33,554,432
  float* xsb  = (float*)(ws + 55050240);                    // 2048x2048 f32 = 16,777,216
  float* proj = (float*)(ws + 71827456);                    // 2048x2080 f32 = 17,039,360
  float* dtb  = (float*)(ws);                               // 2048x2048 f32 (overlay)
  float* vb   = dtb;                                        // v aliases dt (k_scanC)
  float* Ebuf = out;                                        // 1,048,576 f32 (in d_out)
  float* Lbuf = out + 1048576;                              // 1,048,576 f32 (in d_out)

  const dim3 blk(256);
  // weight transpose + bf16 cast
  k_transpose_bf16<<<dim3(4096 / 32, 1024 / 32), blk, 0, stream>>>(w_in, w1t, 1024, 4096);
  k_transpose_bf16<<<dim3(NPROJ_PAD / 32, 2048 / 32), blk, 0, stream>>>(w_xp, w2t, 2048, NPROJ);
  k_transpose_bf16<<<dim3(1024 / 32, 2048 / 32), blk, 0, stream>>>(w_out, w3t, 2048, 1024);
  // xz = x @ in_proj_w + b
  k_gemm<<<dim3(4096 / 128, 2048 / 128), blk, 0, stream>>>(x, 1024, w1t, 1024, b_in, xz, 4096, 1024, 4096);
  // xs = silu(causal_dwconv(xc))
  k_conv_silu<<<dim3(NROWS * DI / 256), blk, 0, stream>>>(xz, cw, cb, xsb);
  // proj = xs @ x_proj_w + b
  k_gemm<<<dim3(NPROJ_PAD / 128, 2048 / 128), blk, 0, stream>>>(xsb, 2048, w2t, 2048, b_xp, proj, NPROJ, 2048, NPROJ);
  // dt = softplus(proj[:, :16] @ dt_proj_w + b)
  k_dtproj<<<dim3(NROWS * DI / 256), blk, 0, stream>>>(proj, w_dt, b_dt, dtb);
  // selective scan (chunk-parallel, s-in-registers) + gate -> v
  k_scanA<<<dim3(TOTCH * 8), blk, 0, stream>>>(dtb, proj, xsb, Alog, Ebuf, Lbuf);
  k_scanB<<<dim3(NB * DI * DS / 256), blk, 0, stream>>>(Ebuf, Lbuf);
  k_scanC<<<dim3(TOTCH * 8), blk, 0, stream>>>(dtb, proj, xsb, xz, Alog, Dp, Ebuf, Lbuf, vb);
  // out = v @ out_proj_w + b
  k_gemm<<<dim3(1024 / 128, 2048 / 128), blk, 0, stream>>>(vb, 2048, w3t, 2048, b_out, out, 1024, 2048, 1024);
}

// Round 7
// 434.121 us; speedup vs baseline: 1.2165x; 1.0631x over previous
//
#include <hip/hip_runtime.h>

#define DI 2048
#define DM 1024
#define DS 16
#define LEN 1024
#define NB 2
#define NROWS (NB * LEN)        // 2048
#define NPROJ (2 * DS + DI)     // 2080
#define NPROJ_PAD 2176
#define N_XZ (2 * DI)           // 4096
#define CH_R 64                 // rows per scan chunk
#define NCH (LEN / CH_R)        // 16 chunks per batch
#define TOTCH (NB * NCH)        // 32 chunks total

using bf16x8 = __attribute__((ext_vector_type(8))) short;
using f32x4  = __attribute__((ext_vector_type(4))) float;

__device__ __forceinline__ unsigned short f32_bf16(float f) {
  unsigned int u = __float_as_uint(f);
  u += 0x7fffu + ((u >> 16) & 1u);   // round-to-nearest-even
  return (unsigned short)(u >> 16);
}
__device__ __forceinline__ unsigned int packbf(float lo, float hi) {
  return (unsigned int)f32_bf16(lo) | ((unsigned int)f32_bf16(hi) << 16);
}

// ---------------- transpose + cast: W (K x N) f32 -> Wt (Npad x K) bf16 -----
__global__ __launch_bounds__(256)
void k_transpose_bf16(const float* __restrict__ W, unsigned short* __restrict__ Wt,
                      int K, int N) {
  __shared__ float tile[32][33];
  const int n0 = blockIdx.x * 32, k0 = blockIdx.y * 32;
  const int tx = threadIdx.x & 31;
  const int ty = threadIdx.x >> 5;
#pragma unroll
  for (int j = 0; j < 32; j += 8) {
    const int n = n0 + tx, k = k0 + ty + j;
    tile[ty + j][tx] = (n < N) ? W[(size_t)k * N + n] : 0.f;  // pad rows -> 0
  }
  __syncthreads();
#pragma unroll
  for (int j = 0; j < 32; j += 8)
    Wt[(size_t)(n0 + ty + j) * K + (k0 + tx)] = f32_bf16(tile[tx][ty + j]);
}

// ---------------- f32-A MFMA GEMM, double-buffered pipelined K-loop ---------
// Same interface/math as the round-2/4/6 passing kernel. New: LDS double
// buffer + register prefetch (global loads for tile k+1 issue before tile k's
// MFMAs) + single barrier per k-step. Staging layout/stride-40 unchanged.
__global__ __launch_bounds__(256)
void k_gemm(const float* __restrict__ A, int lda,
            const unsigned short* __restrict__ Bt, int ldb,
            const float* __restrict__ bias,
            float* __restrict__ C, int ldc,
            int K, int Nlog) {
  __shared__ __align__(16) unsigned short As[2][128 * 40];  // 2 x 10240 B
  __shared__ __align__(16) unsigned short Bs[2][128 * 40];
  const int tid = threadIdx.x;
  const int m0 = blockIdx.y * 128;
  const int n0 = blockIdx.x * 128;
  const int lane = tid & 63;
  const int wid = tid >> 6;
  const int wr = (wid >> 1) * 64, wc = (wid & 1) * 64;
  const int g = lane >> 4, r = lane & 15;

  const int srow = tid >> 1;          // 0..127
  const int scol = (tid & 1) * 16;    // 0 or 16

  const float* Ap = A + (size_t)(m0 + srow) * lda + scol;
  const unsigned short* Bp = Bt + (size_t)(n0 + srow) * ldb + scol;
  const int swoff = srow * 40 + scol;

  f32x4 acc[4][4] = {};
  float4 ra0, ra1, ra2, ra3;
  uint4 rb0, rb1;

#define LOADG(k0) do {                                                        \
    ra0 = *(const float4*)(Ap + (k0));                                        \
    ra1 = *(const float4*)(Ap + (k0) + 4);                                    \
    ra2 = *(const float4*)(Ap + (k0) + 8);                                    \
    ra3 = *(const float4*)(Ap + (k0) + 12);                                   \
    rb0 = *(const uint4*)(Bp + (k0));                                         \
    rb1 = *(const uint4*)(Bp + (k0) + 8);                                     \
  } while (0)

#define STORE(bf) do {                                                        \
    unsigned short* asw = &As[bf][swoff];                                     \
    unsigned short* bsw = &Bs[bf][swoff];                                     \
    *(uint4*)asw = make_uint4(packbf(ra0.x, ra0.y), packbf(ra0.z, ra0.w),     \
                              packbf(ra1.x, ra1.y), packbf(ra1.z, ra1.w));    \
    *(uint4*)(asw + 8) = make_uint4(packbf(ra2.x, ra2.y), packbf(ra2.z, ra2.w),\
                                    packbf(ra3.x, ra3.y), packbf(ra3.z, ra3.w));\
    *(uint4*)bsw = rb0;                                                       \
    *(uint4*)(bsw + 8) = rb1;                                                 \
  } while (0)

#define COMPUTE(bf) do {                                                      \
    bf16x8 af[4], bfr[4];                                                     \
    _Pragma("unroll")                                                         \
    for (int i = 0; i < 4; ++i)                                               \
      af[i] = *(const bf16x8*)&As[bf][(wr + i * 16 + r) * 40 + 8 * g];        \
    _Pragma("unroll")                                                         \
    for (int j = 0; j < 4; ++j)                                               \
      bfr[j] = *(const bf16x8*)&Bs[bf][(wc + j * 16 + r) * 40 + 8 * g];       \
    _Pragma("unroll")                                                         \
    for (int i = 0; i < 4; ++i)                                               \
      _Pragma("unroll")                                                       \
      for (int j = 0; j < 4; ++j)                                             \
        acc[i][j] = __builtin_amdgcn_mfma_f32_16x16x32_bf16(af[i], bfr[j],    \
                                                            acc[i][j], 0, 0, 0);\
  } while (0)

  LOADG(0);
  STORE(0);
  __syncthreads();
  int buf = 0;
  for (int k0 = 32; k0 < K; k0 += 32) {
    LOADG(k0);          // prefetch next tile (latency hides under COMPUTE)
    COMPUTE(buf);
    STORE(buf ^ 1);     // write other buffer; current readers unaffected
    __syncthreads();    // one barrier per k-step
    buf ^= 1;
  }
  COMPUTE(buf);

#undef LOADG
#undef STORE
#undef COMPUTE

#pragma unroll
  for (int i = 0; i < 4; ++i) {
    const int row = m0 + wr + i * 16 + 4 * g;  // C/D: row=(lane>>4)*4+reg
#pragma unroll
    for (int j = 0; j < 4; ++j) {
      const int col = n0 + wc + j * 16 + r;    // C/D: col=lane&15
      if (col < Nlog) {
        const float bv = bias[col];
#pragma unroll
        for (int q = 0; q < 4; ++q)
          C[(size_t)(row + q) * ldc + col] = acc[i][j][q] + bv;
      }
    }
  }
}

// ---------------- causal depthwise conv (k=4) + silu (unchanged) ------------
__global__ __launch_bounds__(256)
void k_conv_silu(const float* __restrict__ xz, const float* __restrict__ cw,
                 const float* __restrict__ cb, float* __restrict__ xs) {
  const int idx = blockIdx.x * 256 + threadIdx.x;   // row*DI + d
  const int d = idx & (DI - 1);
  const int row = idx >> 11;
  const int l = row & (LEN - 1);
  const float w0 = cw[d * 4], w1 = cw[d * 4 + 1], w2 = cw[d * 4 + 2], w3 = cw[d * 4 + 3];
  const float* p = xz + (size_t)row * N_XZ + d;     // xc = first DI cols of xz
  float acc = cb[d] + w3 * p[0];
  if (l >= 1) acc += w2 * p[-N_XZ];
  if (l >= 2) acc += w1 * p[-2 * N_XZ];
  if (l >= 3) acc += w0 * p[-3 * N_XZ];
  xs[idx] = acc / (1.f + expf(-acc));               // silu
}

// ---------------- dt = softplus(proj[:, :16] @ dt_proj_w + b) (unchanged) ---
__global__ __launch_bounds__(256)
void k_dtproj(const float* __restrict__ proj, const float* __restrict__ w,
              const float* __restrict__ b, float* __restrict__ dt) {
  const int idx = blockIdx.x * 256 + threadIdx.x;
  const int d = idx & (DI - 1);
  const int row = idx >> 11;
  const float* p = proj + (size_t)row * NPROJ;
  float acc = b[d];
#pragma unroll
  for (int s = 0; s < DS; ++s) acc += p[s] * w[s * DI + d];
  dt[idx] = fmaxf(acc, 0.f) + log1pf(expf(-fabsf(acc)));  // stable softplus
}

// ---------------- selective scan: chunk-parallel, s-in-registers (unchanged) -
__global__ __launch_bounds__(256)
void k_scanA(const float* __restrict__ dt, const float* __restrict__ proj,
             const float* __restrict__ xs, const float* __restrict__ Alog,
             float* __restrict__ Ebuf, float* __restrict__ Lbuf) {
  __shared__ float bp_lds[CH_R][DS];                // 4 KB
  const int bx = blockIdx.x;                        // 0..255
  const int chunkg = bx >> 3;                       // 0..31
  const int d = (bx & 7) * 256 + threadIdx.x;       // 0..2047
  const int b = chunkg >> 4, c = chunkg & (NCH - 1);
  const int row0 = b * LEN + c * CH_R;
#pragma unroll
  for (int i = 0; i < 4; ++i) {                     // stage 64x16 B-rows
    const int e0 = threadIdx.x + i * 256;
    bp_lds[e0 >> 4][e0 & 15] = proj[(size_t)(row0 + (e0 >> 4)) * NPROJ + DS + (e0 & 15)];
  }
  __syncthreads();

  float a[DS], e[DS], L[DS];
#pragma unroll
  for (int s = 0; s < DS; ++s) {
    a[s] = -expf(Alog[d * DS + s]);
    e[s] = 1.f; L[s] = 0.f;
  }
#pragma unroll 4
  for (int j = 0; j < CH_R; ++j) {
    const size_t row = (size_t)(row0 + j);
    const float dtv = dt[row * DI + d];
    const float xv = xs[row * DI + d];
    const float u = dtv * xv;
#pragma unroll
    for (int q = 0; q < 4; ++q) {
      const float4 bq = *(const float4*)&bp_lds[j][q * 4];
      L[q * 4 + 0] += e[q * 4 + 0] * (u * bq.x);
      L[q * 4 + 1] += e[q * 4 + 1] * (u * bq.y);
      L[q * 4 + 2] += e[q * 4 + 2] * (u * bq.z);
      L[q * 4 + 3] += e[q * 4 + 3] * (u * bq.w);
    }
#pragma unroll
    for (int s = 0; s < DS; ++s)
      e[s] *= __expf(dtv * a[s]) + 1e-8f;
  }
  const size_t base = ((size_t)chunkg * DI + d) * DS;
#pragma unroll
  for (int q = 0; q < 4; ++q) {
    *(float4*)&Ebuf[base + q * 4] = make_float4(e[q*4], e[q*4+1], e[q*4+2], e[q*4+3]);
    *(float4*)&Lbuf[base + q * 4] = make_float4(L[q*4], L[q*4+1], L[q*4+2], L[q*4+3]);
  }
}

__global__ __launch_bounds__(256)
void k_scanB(float* __restrict__ Ebuf, float* __restrict__ Lbuf) {
  const int gid = blockIdx.x * 256 + threadIdx.x;   // b*32768 + d*16 + s
  const int s = gid & 15, d = (gid >> 4) & (DI - 1), b = gid >> 15;
  float scale = 1.f, H = 0.f;
#pragma unroll
  for (int c = 0; c < NCH; ++c) {
    const size_t idx = (((size_t)(b * NCH + c) * DI + d) << 4) + s;
    const float E = Ebuf[idx], Ls = Lbuf[idx];
    Ebuf[idx] = scale;                              // chunk-start scale
    Lbuf[idx] = H;                                  // chunk-start H
    H += scale * Ls;
    scale *= E;
  }
}

// dt and v ALIAS (same buffer): intentionally NOT __restrict__ so the
// compiler preserves per-address load-before-store order.
__global__ __launch_bounds__(256)
void k_scanC(const float* dt, const float* __restrict__ proj,
             const float* __restrict__ xs, const float* __restrict__ xz,
             const float* __restrict__ Alog, const float* __restrict__ Dp,
             const float* __restrict__ Ebuf, const float* __restrict__ Lbuf,
             float* v) {
  __shared__ float bp_lds[CH_R][DS];
  const int bx = blockIdx.x;
  const int chunkg = bx >> 3;
  const int d = (bx & 7) * 256 + threadIdx.x;
  const int b = chunkg >> 4, c = chunkg & (NCH - 1);
  const int row0 = b * LEN + c * CH_R;
#pragma unroll
  for (int i = 0; i < 4; ++i) {
    const int e0 = threadIdx.x + i * 256;
    bp_lds[e0 >> 4][e0 & 15] = proj[(size_t)(row0 + (e0 >> 4)) * NPROJ + DS + (e0 & 15)];
  }
  __syncthreads();

  const float Dd = Dp[d];
  float a[DS], e[DS], h[DS];
  const size_t base = ((size_t)chunkg * DI + d) * DS;
#pragma unroll
  for (int q = 0; q < 4; ++q) {
    const float4 ev = *(const float4*)&Ebuf[base + q * 4];
    const float4 hv = *(const float4*)&Lbuf[base + q * 4];
    e[q*4] = ev.x; e[q*4+1] = ev.y; e[q*4+2] = ev.z; e[q*4+3] = ev.w;
    h[q*4] = hv.x; h[q*4+1] = hv.y; h[q*4+2] = hv.z; h[q*4+3] = hv.w;
  }
#pragma unroll
  for (int s = 0; s < DS; ++s)
    a[s] = -expf(Alog[d * DS + s]);

#pragma unroll 4
  for (int j = 0; j < CH_R; ++j) {
    const size_t row = (size_t)(row0 + j);
    const float dtv = dt[row * DI + d];             // read BEFORE v-store (alias)
    const float xv = xs[row * DI + d];
    const float u = dtv * xv;
#pragma unroll
    for (int q = 0; q < 4; ++q) {
      const float4 bq = *(const float4*)&bp_lds[j][q * 4];
      h[q * 4 + 0] += e[q * 4 + 0] * (u * bq.x);
      h[q * 4 + 1] += e[q * 4 + 1] * (u * bq.y);
      h[q * 4 + 2] += e[q * 4 + 2] * (u * bq.z);
      h[q * 4 + 3] += e[q * 4 + 3] * (u * bq.w);
    }
    float hs = 0.f;
#pragma unroll
    for (int s = 0; s < DS; ++s) hs += h[s];
    const float cp = proj[row * NPROJ + 2 * DS + d];
    const float z = xz[row * N_XZ + DI + d];
    const float y = cp * hs + xv * Dd;
    v[row * DI + d] = y * (z / (1.f + __expf(-z)));
#pragma unroll
    for (int s = 0; s < DS; ++s)
      e[s] *= __expf(dtv * a[s]) + 1e-8f;
  }
}

extern "C" void kernel_launch(void* const* d_in, const int* in_sizes, int n_in,
                              void* d_out, int out_size, void* d_ws, size_t ws_size,
                              hipStream_t stream) {
  const float* x     = (const float*)d_in[0];
  const float* w_in  = (const float*)d_in[1];
  const float* b_in  = (const float*)d_in[2];
  const float* cw    = (const float*)d_in[3];
  const float* cb    = (const float*)d_in[4];
  const float* w_xp  = (const float*)d_in[5];
  const float* b_xp  = (const float*)d_in[6];
  const float* w_dt  = (const float*)d_in[7];
  const float* b_dt  = (const float*)d_in[8];
  const float* Alog  = (const float*)d_in[9];
  const float* Dp    = (const float*)d_in[10];
  const float* w_out = (const float*)d_in[11];
  const float* b_out = (const float*)d_in[12];
  float* out = (float*)d_out;

  // workspace layout: IDENTICAL to the round-4/6 passing layout (max 88,866,816 B).
  char* ws = (char*)d_ws;
  unsigned short* w1t = (unsigned short*)(ws);              // 4096x1024 bf16 =  8,388,608
  unsigned short* w2t = (unsigned short*)(ws + 8388608);    // 2176x2048 bf16 =  8,912,896
  unsigned short* w3t = (unsigned short*)(ws + 17301504);   // 1024x2048 bf16 =  4,194,304
  float* xz   = (float*)(ws + 21495808);                    // 2048x4096 f32 = 33,554,432
  float* xsb  = (float*)(ws + 55050240);                    // 2048x2048 f32 = 16,777,216
  float* proj = (float*)(ws + 71827456);                    // 2048x2080 f32 = 17,039,360
  float* dtb  = (float*)(ws);                               // 2048x2048 f32 (overlay)
  float* vb   = dtb;                                        // v aliases dt (k_scanC)
  float* Ebuf = out;                                        // 1,048,576 f32 (in d_out)
  float* Lbuf = out + 1048576;                              // 1,048,576 f32 (in d_out)

  const dim3 blk(256);
  // weight transpose + bf16 cast
  k_transpose_bf16<<<dim3(4096 / 32, 1024 / 32), blk, 0, stream>>>(w_in, w1t, 1024, 4096);
  k_transpose_bf16<<<dim3(NPROJ_PAD / 32, 2048 / 32), blk, 0, stream>>>(w_xp, w2t, 2048, NPROJ);
  k_transpose_bf16<<<dim3(1024 / 32, 2048 / 32), blk, 0, stream>>>(w_out, w3t, 2048, 1024);
  // xz = x @ in_proj_w + b
  k_gemm<<<dim3(4096 / 128, 2048 / 128), blk, 0, stream>>>(x, 1024, w1t, 1024, b_in, xz, 4096, 1024, 4096);
  // xs = silu(causal_dwconv(xc))
  k_conv_silu<<<dim3(NROWS * DI / 256), blk, 0, stream>>>(xz, cw, cb, xsb);
  // proj = xs @ x_proj_w + b
  k_gemm<<<dim3(NPROJ_PAD / 128, 2048 / 128), blk, 0, stream>>>(xsb, 2048, w2t, 2048, b_xp, proj, NPROJ, 2048, NPROJ);
  // dt = softplus(proj[:, :16] @ dt_proj_w + b)
  k_dtproj<<<dim3(NROWS * DI / 256), blk, 0, stream>>>(proj, w_dt, b_dt, dtb);
  // selective scan (chunk-parallel, s-in-registers) + gate -> v
  k_scanA<<<dim3(TOTCH * 8), blk, 0, stream>>>(dtb, proj, xsb, Alog, Ebuf, Lbuf);
  k_scanB<<<dim3(NB * DI * DS / 256), blk, 0, stream>>>(Ebuf, Lbuf);
  k_scanC<<<dim3(TOTCH * 8), blk, 0, stream>>>(dtb, proj, xsb, xz, Alog, Dp, Ebuf, Lbuf, vb);
  // out = v @ out_proj_w + b
  k_gemm<<<dim3(1024 / 128, 2048 / 128), blk, 0, stream>>>(vb, 2048, w3t, 2048, b_out, out, 1024, 2048, 1024);
}

// Round 8
// 380.536 us; speedup vs baseline: 1.3878x; 1.1408x over previous
//
#include <hip/hip_runtime.h>

#define DI 2048
#define DM 1024
#define DS 16
#define LEN 1024
#define NB 2
#define NROWS (NB * LEN)        // 2048
#define NPROJ (2 * DS + DI)     // 2080
#define NPROJ_PAD 2176
#define N_XZ (2 * DI)           // 4096
#define CH_R 64                 // rows per scan chunk
#define NCH (LEN / CH_R)        // 16 chunks per batch
#define TOTCH (NB * NCH)        // 32 chunks total

using bf16x8 = __attribute__((ext_vector_type(8))) short;
using f32x4  = __attribute__((ext_vector_type(4))) float;

__device__ __forceinline__ unsigned short f32_bf16(float f) {
  unsigned int u = __float_as_uint(f);
  u += 0x7fffu + ((u >> 16) & 1u);   // round-to-nearest-even
  return (unsigned short)(u >> 16);
}
__device__ __forceinline__ float bf16_f32(unsigned short h) {
  return __uint_as_float((unsigned int)h << 16);
}

// ---------------- transpose + cast: W (K x N) f32 -> Wt (Npad x K) bf16 -----
__global__ __launch_bounds__(256)
void k_transpose_bf16(const float* __restrict__ W, unsigned short* __restrict__ Wt,
                      int K, int N) {
  __shared__ float tile[32][33];
  const int n0 = blockIdx.x * 32, k0 = blockIdx.y * 32;
  const int tx = threadIdx.x & 31;
  const int ty = threadIdx.x >> 5;
#pragma unroll
  for (int j = 0; j < 32; j += 8) {
    const int n = n0 + tx, k = k0 + ty + j;
    tile[ty + j][tx] = (n < N) ? W[(size_t)k * N + n] : 0.f;  // pad rows -> 0
  }
  __syncthreads();
#pragma unroll
  for (int j = 0; j < 32; j += 8)
    Wt[(size_t)(n0 + ty + j) * K + (k0 + tx)] = f32_bf16(tile[tx][ty + j]);
}

// ---------------- elementwise cast f32 -> bf16 (8/thread) -------------------
__global__ __launch_bounds__(256)
void k_cast_bf16(const float* __restrict__ in, unsigned short* __restrict__ out) {
  const int i8 = (blockIdx.x * 256 + threadIdx.x) * 8;
  const float4 a = *(const float4*)(in + i8);
  const float4 b = *(const float4*)(in + i8 + 4);
  ushort4 lo, hi;
  lo.x = f32_bf16(a.x); lo.y = f32_bf16(a.y); lo.z = f32_bf16(a.z); lo.w = f32_bf16(a.w);
  hi.x = f32_bf16(b.x); hi.y = f32_bf16(b.y); hi.z = f32_bf16(b.z); hi.w = f32_bf16(b.w);
  *(ushort4*)(out + i8) = lo;
  *(ushort4*)(out + i8 + 4) = hi;
}

// ---------------- bf16-A MFMA GEMM, double-buffered pipelined K-loop --------
// r7's proven dbuf structure; staging is now pure uint4 bf16 copies (A bf16).
// C(MxN f32) = A(MxK bf16) * Bt(NxK bf16)^T + bias. 128x128 tile, 4 waves.
__global__ __launch_bounds__(256)
void k_gemm_bf(const unsigned short* __restrict__ A, int lda,
               const unsigned short* __restrict__ Bt, int ldb,
               const float* __restrict__ bias,
               float* __restrict__ C, int ldc,
               int K, int Nlog) {
  __shared__ __align__(16) unsigned short As[2][128 * 40];  // 2 x 10240 B
  __shared__ __align__(16) unsigned short Bs[2][128 * 40];
  const int tid = threadIdx.x;
  const int m0 = blockIdx.y * 128;
  const int n0 = blockIdx.x * 128;
  const int lane = tid & 63;
  const int wid = tid >> 6;
  const int wr = (wid >> 1) * 64, wc = (wid & 1) * 64;
  const int g = lane >> 4, r = lane & 15;

  const int srow = tid >> 1;          // 0..127
  const int scol = (tid & 1) * 16;    // 0 or 16

  const unsigned short* Ap = A + (size_t)(m0 + srow) * lda + scol;
  const unsigned short* Bp = Bt + (size_t)(n0 + srow) * ldb + scol;
  const int swoff = srow * 40 + scol;

  f32x4 acc[4][4] = {};
  uint4 ra0, ra1, rb0, rb1;

#define LOADG(k0) do {                                                        \
    ra0 = *(const uint4*)(Ap + (k0));                                         \
    ra1 = *(const uint4*)(Ap + (k0) + 8);                                     \
    rb0 = *(const uint4*)(Bp + (k0));                                         \
    rb1 = *(const uint4*)(Bp + (k0) + 8);                                     \
  } while (0)

#define STORE(bf) do {                                                        \
    unsigned short* asw = &As[bf][swoff];                                     \
    unsigned short* bsw = &Bs[bf][swoff];                                     \
    *(uint4*)asw = ra0;                                                       \
    *(uint4*)(asw + 8) = ra1;                                                 \
    *(uint4*)bsw = rb0;                                                       \
    *(uint4*)(bsw + 8) = rb1;                                                 \
  } while (0)

#define COMPUTE(bf) do {                                                      \
    bf16x8 af[4], bfr[4];                                                     \
    _Pragma("unroll")                                                         \
    for (int i = 0; i < 4; ++i)                                               \
      af[i] = *(const bf16x8*)&As[bf][(wr + i * 16 + r) * 40 + 8 * g];        \
    _Pragma("unroll")                                                         \
    for (int j = 0; j < 4; ++j)                                               \
      bfr[j] = *(const bf16x8*)&Bs[bf][(wc + j * 16 + r) * 40 + 8 * g];       \
    _Pragma("unroll")                                                         \
    for (int i = 0; i < 4; ++i)                                               \
      _Pragma("unroll")                                                       \
      for (int j = 0; j < 4; ++j)                                             \
        acc[i][j] = __builtin_amdgcn_mfma_f32_16x16x32_bf16(af[i], bfr[j],    \
                                                            acc[i][j], 0, 0, 0);\
  } while (0)

  LOADG(0);
  STORE(0);
  __syncthreads();
  int buf = 0;
  for (int k0 = 32; k0 < K; k0 += 32) {
    LOADG(k0);          // prefetch next tile (latency hides under COMPUTE)
    COMPUTE(buf);
    STORE(buf ^ 1);     // write other buffer; current readers unaffected
    __syncthreads();    // one barrier per k-step
    buf ^= 1;
  }
  COMPUTE(buf);

#undef LOADG
#undef STORE
#undef COMPUTE

#pragma unroll
  for (int i = 0; i < 4; ++i) {
    const int row = m0 + wr + i * 16 + 4 * g;  // C/D: row=(lane>>4)*4+reg
#pragma unroll
    for (int j = 0; j < 4; ++j) {
      const int col = n0 + wc + j * 16 + r;    // C/D: col=lane&15
      if (col < Nlog) {
        const float bv = bias[col];
#pragma unroll
        for (int q = 0; q < 4; ++q)
          C[(size_t)(row + q) * ldc + col] = acc[i][j][q] + bv;
      }
    }
  }
}

// ---------------- causal depthwise conv (k=4) + silu -> bf16 xs -------------
__global__ __launch_bounds__(256)
void k_conv_silu(const float* __restrict__ xz, const float* __restrict__ cw,
                 const float* __restrict__ cb, unsigned short* __restrict__ xs) {
  const int idx = blockIdx.x * 256 + threadIdx.x;   // row*DI + d
  const int d = idx & (DI - 1);
  const int row = idx >> 11;
  const int l = row & (LEN - 1);
  const float w0 = cw[d * 4], w1 = cw[d * 4 + 1], w2 = cw[d * 4 + 2], w3 = cw[d * 4 + 3];
  const float* p = xz + (size_t)row * N_XZ + d;     // xc = first DI cols of xz
  float acc = cb[d] + w3 * p[0];
  if (l >= 1) acc += w2 * p[-N_XZ];
  if (l >= 2) acc += w1 * p[-2 * N_XZ];
  if (l >= 3) acc += w0 * p[-3 * N_XZ];
  xs[idx] = f32_bf16(acc / (1.f + expf(-acc)));     // silu, bf16
}

// ---------------- dt = softplus(proj[:, :16] @ dt_proj_w + b) (unchanged) ---
__global__ __launch_bounds__(256)
void k_dtproj(const float* __restrict__ proj, const float* __restrict__ w,
              const float* __restrict__ b, float* __restrict__ dt) {
  const int idx = blockIdx.x * 256 + threadIdx.x;
  const int d = idx & (DI - 1);
  const int row = idx >> 11;
  const float* p = proj + (size_t)row * NPROJ;
  float acc = b[d];
#pragma unroll
  for (int s = 0; s < DS; ++s) acc += p[s] * w[s * DI + d];
  dt[idx] = fmaxf(acc, 0.f) + log1pf(expf(-fabsf(acc)));  // stable softplus
}

// ---------------- selective scan: chunk-parallel, s-in-registers ------------
// Proven r6/r7 algebra; xs is now bf16; v written as bf16 to a SEPARATE
// buffer (no aliasing -> no cross-width race).
__global__ __launch_bounds__(256)
void k_scanA(const float* __restrict__ dt, const float* __restrict__ proj,
             const unsigned short* __restrict__ xs, const float* __restrict__ Alog,
             float* __restrict__ Ebuf, float* __restrict__ Lbuf) {
  __shared__ float bp_lds[CH_R][DS];                // 4 KB
  const int bx = blockIdx.x;                        // 0..255
  const int chunkg = bx >> 3;                       // 0..31
  const int d = (bx & 7) * 256 + threadIdx.x;       // 0..2047
  const int b = chunkg >> 4, c = chunkg & (NCH - 1);
  const int row0 = b * LEN + c * CH_R;
#pragma unroll
  for (int i = 0; i < 4; ++i) {                     // stage 64x16 B-rows
    const int e0 = threadIdx.x + i * 256;
    bp_lds[e0 >> 4][e0 & 15] = proj[(size_t)(row0 + (e0 >> 4)) * NPROJ + DS + (e0 & 15)];
  }
  __syncthreads();

  float a[DS], e[DS], L[DS];
#pragma unroll
  for (int s = 0; s < DS; ++s) {
    a[s] = -expf(Alog[d * DS + s]);
    e[s] = 1.f; L[s] = 0.f;
  }
#pragma unroll 4
  for (int j = 0; j < CH_R; ++j) {
    const size_t row = (size_t)(row0 + j);
    const float dtv = dt[row * DI + d];
    const float xv = bf16_f32(xs[row * DI + d]);
    const float u = dtv * xv;
#pragma unroll
    for (int q = 0; q < 4; ++q) {
      const float4 bq = *(const float4*)&bp_lds[j][q * 4];
      L[q * 4 + 0] += e[q * 4 + 0] * (u * bq.x);
      L[q * 4 + 1] += e[q * 4 + 1] * (u * bq.y);
      L[q * 4 + 2] += e[q * 4 + 2] * (u * bq.z);
      L[q * 4 + 3] += e[q * 4 + 3] * (u * bq.w);
    }
#pragma unroll
    for (int s = 0; s < DS; ++s)
      e[s] *= __expf(dtv * a[s]) + 1e-8f;
  }
  const size_t base = ((size_t)chunkg * DI + d) * DS;
#pragma unroll
  for (int q = 0; q < 4; ++q) {
    *(float4*)&Ebuf[base + q * 4] = make_float4(e[q*4], e[q*4+1], e[q*4+2], e[q*4+3]);
    *(float4*)&Lbuf[base + q * 4] = make_float4(L[q*4], L[q*4+1], L[q*4+2], L[q*4+3]);
  }
}

__global__ __launch_bounds__(256)
void k_scanB(float* __restrict__ Ebuf, float* __restrict__ Lbuf) {
  const int gid = blockIdx.x * 256 + threadIdx.x;   // b*32768 + d*16 + s
  const int s = gid & 15, d = (gid >> 4) & (DI - 1), b = gid >> 15;
  float scale = 1.f, H = 0.f;
#pragma unroll
  for (int c = 0; c < NCH; ++c) {
    const size_t idx = (((size_t)(b * NCH + c) * DI + d) << 4) + s;
    const float E = Ebuf[idx], Ls = Lbuf[idx];
    Ebuf[idx] = scale;                              // chunk-start scale
    Lbuf[idx] = H;                                  // chunk-start H
    H += scale * Ls;
    scale *= E;
  }
}

__global__ __launch_bounds__(256)
void k_scanC(const float* __restrict__ dt, const float* __restrict__ proj,
             const unsigned short* __restrict__ xs, const float* __restrict__ xz,
             const float* __restrict__ Alog, const float* __restrict__ Dp,
             const float* __restrict__ Ebuf, const float* __restrict__ Lbuf,
             unsigned short* __restrict__ v) {
  __shared__ float bp_lds[CH_R][DS];
  const int bx = blockIdx.x;
  const int chunkg = bx >> 3;
  const int d = (bx & 7) * 256 + threadIdx.x;
  const int b = chunkg >> 4, c = chunkg & (NCH - 1);
  const int row0 = b * LEN + c * CH_R;
#pragma unroll
  for (int i = 0; i < 4; ++i) {
    const int e0 = threadIdx.x + i * 256;
    bp_lds[e0 >> 4][e0 & 15] = proj[(size_t)(row0 + (e0 >> 4)) * NPROJ + DS + (e0 & 15)];
  }
  __syncthreads();

  const float Dd = Dp[d];
  float a[DS], e[DS], h[DS];
  const size_t base = ((size_t)chunkg * DI + d) * DS;
#pragma unroll
  for (int q = 0; q < 4; ++q) {
    const float4 ev = *(const float4*)&Ebuf[base + q * 4];
    const float4 hv = *(const float4*)&Lbuf[base + q * 4];
    e[q*4] = ev.x; e[q*4+1] = ev.y; e[q*4+2] = ev.z; e[q*4+3] = ev.w;
    h[q*4] = hv.x; h[q*4+1] = hv.y; h[q*4+2] = hv.z; h[q*4+3] = hv.w;
  }
#pragma unroll
  for (int s = 0; s < DS; ++s)
    a[s] = -expf(Alog[d * DS + s]);

#pragma unroll 4
  for (int j = 0; j < CH_R; ++j) {
    const size_t row = (size_t)(row0 + j);
    const float dtv = dt[row * DI + d];
    const float xv = bf16_f32(xs[row * DI + d]);
    const float u = dtv * xv;
#pragma unroll
    for (int q = 0; q < 4; ++q) {
      const float4 bq = *(const float4*)&bp_lds[j][q * 4];
      h[q * 4 + 0] += e[q * 4 + 0] * (u * bq.x);
      h[q * 4 + 1] += e[q * 4 + 1] * (u * bq.y);
      h[q * 4 + 2] += e[q * 4 + 2] * (u * bq.z);
      h[q * 4 + 3] += e[q * 4 + 3] * (u * bq.w);
    }
    float hs = 0.f;
#pragma unroll
    for (int s = 0; s < DS; ++s) hs += h[s];
    const float cp = proj[row * NPROJ + 2 * DS + d];
    const float z = xz[row * N_XZ + DI + d];        // z stays f32
    const float y = cp * hs + xv * Dd;
    v[row * DI + d] = f32_bf16(y * (z / (1.f + __expf(-z))));
#pragma unroll
    for (int s = 0; s < DS; ++s)
      e[s] *= __expf(dtv * a[s]) + 1e-8f;
  }
}

extern "C" void kernel_launch(void* const* d_in, const int* in_sizes, int n_in,
                              void* d_out, int out_size, void* d_ws, size_t ws_size,
                              hipStream_t stream) {
  const float* x     = (const float*)d_in[0];
  const float* w_in  = (const float*)d_in[1];
  const float* b_in  = (const float*)d_in[2];
  const float* cw    = (const float*)d_in[3];
  const float* cb    = (const float*)d_in[4];
  const float* w_xp  = (const float*)d_in[5];
  const float* b_xp  = (const float*)d_in[6];
  const float* w_dt  = (const float*)d_in[7];
  const float* b_dt  = (const float*)d_in[8];
  const float* Alog  = (const float*)d_in[9];
  const float* Dp    = (const float*)d_in[10];
  const float* w_out = (const float*)d_in[11];
  const float* b_out = (const float*)d_in[12];
  float* out = (float*)d_out;

  // workspace layout, high-water 101,449,728 B < proven-safe 105,644,032 (r2).
  // Lifetimes: w1t dead after gemm1; w2t dead after gemm2; dtb overlays
  // w1t+w2t (written post-gemm2 by dtproj, ends 16,777,216 < w3t@17,301,504);
  // xbf dead after gemm1; xz live through scanC (z column); xsb live through
  // scanC; vb SEPARATE (no alias). Ebuf/Lbuf in d_out (2x4 MB = exactly
  // out_size; dead until gemm3 overwrites d_out).
  char* ws = (char*)d_ws;
  unsigned short* w1t = (unsigned short*)(ws);              // 4096x1024 bf16 =  8,388,608
  unsigned short* w2t = (unsigned short*)(ws + 8388608);    // 2176x2048 bf16 =  8,912,896
  unsigned short* w3t = (unsigned short*)(ws + 17301504);   // 1024x2048 bf16 =  4,194,304
  unsigned short* xbf = (unsigned short*)(ws + 21495808);   // 2048x1024 bf16 =  4,194,304
  float* xz   = (float*)(ws + 25690112);                    // 2048x4096 f32 = 33,554,432
  unsigned short* xsb = (unsigned short*)(ws + 59244544);   // 2048x2048 bf16 =  8,388,608
  float* proj = (float*)(ws + 76021760);                    // 2048x2080 f32 = 17,039,360 -> 93,061,120
  unsigned short* vb  = (unsigned short*)(ws + 93061120);   // 2048x2048 bf16 =  8,388,608 -> 101,449,728
  float* dtb  = (float*)(ws);                               // 2048x2048 f32 (overlay w1t+w2t)
  float* Ebuf = out;                                        // 1,048,576 f32 (in d_out)
  float* Lbuf = out + 1048576;                              // 1,048,576 f32 (in d_out)

  const dim3 blk(256);
  // weight transpose + bf16 cast
  k_transpose_bf16<<<dim3(4096 / 32, 1024 / 32), blk, 0, stream>>>(w_in, w1t, 1024, 4096);
  k_transpose_bf16<<<dim3(NPROJ_PAD / 32, 2048 / 32), blk, 0, stream>>>(w_xp, w2t, 2048, NPROJ);
  k_transpose_bf16<<<dim3(1024 / 32, 2048 / 32), blk, 0, stream>>>(w_out, w3t, 2048, 1024);
  k_cast_bf16<<<dim3(NROWS * DM / (256 * 8)), blk, 0, stream>>>(x, xbf);
  // xz = x @ in_proj_w + b
  k_gemm_bf<<<dim3(4096 / 128, 2048 / 128), blk, 0, stream>>>(xbf, 1024, w1t, 1024, b_in, xz, 4096, 1024, 4096);
  // xs = silu(causal_dwconv(xc)) [bf16]
  k_conv_silu<<<dim3(NROWS * DI / 256), blk, 0, stream>>>(xz, cw, cb, xsb);
  // proj = xs @ x_proj_w + b
  k_gemm_bf<<<dim3(NPROJ_PAD / 128, 2048 / 128), blk, 0, stream>>>(xsb, 2048, w2t, 2048, b_xp, proj, NPROJ, 2048, NPROJ);
  // dt = softplus(proj[:, :16] @ dt_proj_w + b)
  k_dtproj<<<dim3(NROWS * DI / 256), blk, 0, stream>>>(proj, w_dt, b_dt, dtb);
  // selective scan (chunk-parallel, s-in-registers) + gate -> v (bf16)
  k_scanA<<<dim3(TOTCH * 8), blk, 0, stream>>>(dtb, proj, xsb, Alog, Ebuf, Lbuf);
  k_scanB<<<dim3(NB * DI * DS / 256), blk, 0, stream>>>(Ebuf, Lbuf);
  k_scanC<<<dim3(TOTCH * 8), blk, 0, stream>>>(dtb, proj, xsb, xz, Alog, Dp, Ebuf, Lbuf, vb);
  // out = v @ out_proj_w + b
  k_gemm_bf<<<dim3(1024 / 128, 2048 / 128), blk, 0, stream>>>(vb, 2048, w3t, 2048, b_out, out, 1024, 2048, 1024);
}

// Round 9
// 345.914 us; speedup vs baseline: 1.5267x; 1.1001x over previous
//
#include <hip/hip_runtime.h>

#define DI 2048
#define DM 1024
#define DS 16
#define LEN 1024
#define NB 2
#define NROWS (NB * LEN)        // 2048
#define NPROJ (2 * DS + DI)     // 2080
#define NPROJ_PAD 2176
#define N_XZ (2 * DI)           // 4096
#define CH_R 16                 // rows per scan chunk
#define NCH (LEN / CH_R)        // 64 chunks per batch
#define TOTCH (NB * NCH)        // 128 chunks total

using bf16x8 = __attribute__((ext_vector_type(8))) short;
using f32x4  = __attribute__((ext_vector_type(4))) float;

__device__ __forceinline__ unsigned short f32_bf16(float f) {
  unsigned int u = __float_as_uint(f);
  u += 0x7fffu + ((u >> 16) & 1u);   // round-to-nearest-even
  return (unsigned short)(u >> 16);
}
__device__ __forceinline__ float bf16_f32(unsigned short h) {
  return __uint_as_float((unsigned int)h << 16);
}

// ---------------- transpose + cast: W (K x N) f32 -> Wt (Npad x K) bf16 -----
__global__ __launch_bounds__(256)
void k_transpose_bf16(const float* __restrict__ W, unsigned short* __restrict__ Wt,
                      int K, int N) {
  __shared__ float tile[32][33];
  const int n0 = blockIdx.x * 32, k0 = blockIdx.y * 32;
  const int tx = threadIdx.x & 31;
  const int ty = threadIdx.x >> 5;
#pragma unroll
  for (int j = 0; j < 32; j += 8) {
    const int n = n0 + tx, k = k0 + ty + j;
    tile[ty + j][tx] = (n < N) ? W[(size_t)k * N + n] : 0.f;  // pad rows -> 0
  }
  __syncthreads();
#pragma unroll
  for (int j = 0; j < 32; j += 8)
    Wt[(size_t)(n0 + ty + j) * K + (k0 + tx)] = f32_bf16(tile[tx][ty + j]);
}

// ---------------- elementwise cast f32 -> bf16 (8/thread) -------------------
__global__ __launch_bounds__(256)
void k_cast_bf16(const float* __restrict__ in, unsigned short* __restrict__ out) {
  const int i8 = (blockIdx.x * 256 + threadIdx.x) * 8;
  const float4 a = *(const float4*)(in + i8);
  const float4 b = *(const float4*)(in + i8 + 4);
  ushort4 lo, hi;
  lo.x = f32_bf16(a.x); lo.y = f32_bf16(a.y); lo.z = f32_bf16(a.z); lo.w = f32_bf16(a.w);
  hi.x = f32_bf16(b.x); hi.y = f32_bf16(b.y); hi.z = f32_bf16(b.z); hi.w = f32_bf16(b.w);
  *(ushort4*)(out + i8) = lo;
  *(ushort4*)(out + i8 + 4) = hi;
}

// ---------------- bf16 MFMA GEMM, double-buffered pipelined K-loop ----------
// (r8 passing version, unchanged)
__global__ __launch_bounds__(256)
void k_gemm_bf(const unsigned short* __restrict__ A, int lda,
               const unsigned short* __restrict__ Bt, int ldb,
               const float* __restrict__ bias,
               float* __restrict__ C, int ldc,
               int K, int Nlog) {
  __shared__ __align__(16) unsigned short As[2][128 * 40];  // 2 x 10240 B
  __shared__ __align__(16) unsigned short Bs[2][128 * 40];
  const int tid = threadIdx.x;
  const int m0 = blockIdx.y * 128;
  const int n0 = blockIdx.x * 128;
  const int lane = tid & 63;
  const int wid = tid >> 6;
  const int wr = (wid >> 1) * 64, wc = (wid & 1) * 64;
  const int g = lane >> 4, r = lane & 15;

  const int srow = tid >> 1;          // 0..127
  const int scol = (tid & 1) * 16;    // 0 or 16

  const unsigned short* Ap = A + (size_t)(m0 + srow) * lda + scol;
  const unsigned short* Bp = Bt + (size_t)(n0 + srow) * ldb + scol;
  const int swoff = srow * 40 + scol;

  f32x4 acc[4][4] = {};
  uint4 ra0, ra1, rb0, rb1;

#define LOADG(k0) do {                                                        \
    ra0 = *(const uint4*)(Ap + (k0));                                         \
    ra1 = *(const uint4*)(Ap + (k0) + 8);                                     \
    rb0 = *(const uint4*)(Bp + (k0));                                         \
    rb1 = *(const uint4*)(Bp + (k0) + 8);                                     \
  } while (0)

#define STORE(bf) do {                                                        \
    unsigned short* asw = &As[bf][swoff];                                     \
    unsigned short* bsw = &Bs[bf][swoff];                                     \
    *(uint4*)asw = ra0;                                                       \
    *(uint4*)(asw + 8) = ra1;                                                 \
    *(uint4*)bsw = rb0;                                                       \
    *(uint4*)(bsw + 8) = rb1;                                                 \
  } while (0)

#define COMPUTE(bf) do {                                                      \
    bf16x8 af[4], bfr[4];                                                     \
    _Pragma("unroll")                                                         \
    for (int i = 0; i < 4; ++i)                                               \
      af[i] = *(const bf16x8*)&As[bf][(wr + i * 16 + r) * 40 + 8 * g];        \
    _Pragma("unroll")                                                         \
    for (int j = 0; j < 4; ++j)                                               \
      bfr[j] = *(const bf16x8*)&Bs[bf][(wc + j * 16 + r) * 40 + 8 * g];       \
    _Pragma("unroll")                                                         \
    for (int i = 0; i < 4; ++i)                                               \
      _Pragma("unroll")                                                       \
      for (int j = 0; j < 4; ++j)                                             \
        acc[i][j] = __builtin_amdgcn_mfma_f32_16x16x32_bf16(af[i], bfr[j],    \
                                                            acc[i][j], 0, 0, 0);\
  } while (0)

  LOADG(0);
  STORE(0);
  __syncthreads();
  int buf = 0;
  for (int k0 = 32; k0 < K; k0 += 32) {
    LOADG(k0);          // prefetch next tile (latency hides under COMPUTE)
    COMPUTE(buf);
    STORE(buf ^ 1);     // write other buffer; current readers unaffected
    __syncthreads();    // one barrier per k-step
    buf ^= 1;
  }
  COMPUTE(buf);

#undef LOADG
#undef STORE
#undef COMPUTE

#pragma unroll
  for (int i = 0; i < 4; ++i) {
    const int row = m0 + wr + i * 16 + 4 * g;  // C/D: row=(lane>>4)*4+reg
#pragma unroll
    for (int j = 0; j < 4; ++j) {
      const int col = n0 + wc + j * 16 + r;    // C/D: col=lane&15
      if (col < Nlog) {
        const float bv = bias[col];
#pragma unroll
        for (int q = 0; q < 4; ++q)
          C[(size_t)(row + q) * ldc + col] = acc[i][j][q] + bv;
      }
    }
  }
}

// ---------------- causal depthwise conv (k=4) + silu -> bf16 xs; compact z --
// zbf is NROWS*DI bf16 = 8,388,608 B (the r3/r5 bug was allocating half this).
__global__ __launch_bounds__(256)
void k_conv_silu_z(const float* __restrict__ xz, const float* __restrict__ cw,
                   const float* __restrict__ cb,
                   unsigned short* __restrict__ xs, unsigned short* __restrict__ zb) {
  const int idx = blockIdx.x * 256 + threadIdx.x;   // row*DI + d
  const int d = idx & (DI - 1);
  const int row = idx >> 11;
  const int l = row & (LEN - 1);
  const float w0 = cw[d * 4], w1 = cw[d * 4 + 1], w2 = cw[d * 4 + 2], w3 = cw[d * 4 + 3];
  const float* p = xz + (size_t)row * N_XZ + d;     // xc = first DI cols of xz
  float acc = cb[d] + w3 * p[0];
  if (l >= 1) acc += w2 * p[-N_XZ];
  if (l >= 2) acc += w1 * p[-2 * N_XZ];
  if (l >= 3) acc += w0 * p[-3 * N_XZ];
  xs[idx] = f32_bf16(acc / (1.f + expf(-acc)));     // silu, bf16
  zb[idx] = f32_bf16(p[DI]);                        // z = xz[row, DI + d]
}

// ---------------- dt = softplus(proj[:, :16] @ dt_proj_w + b) (unchanged) ---
__global__ __launch_bounds__(256)
void k_dtproj(const float* __restrict__ proj, const float* __restrict__ w,
              const float* __restrict__ b, float* __restrict__ dt) {
  const int idx = blockIdx.x * 256 + threadIdx.x;
  const int d = idx & (DI - 1);
  const int row = idx >> 11;
  const float* p = proj + (size_t)row * NPROJ;
  float acc = b[d];
#pragma unroll
  for (int s = 0; s < DS; ++s) acc += p[s] * w[s * DI + d];
  dt[idx] = fmaxf(acc, 0.f) + log1pf(expf(-fabsf(acc)));  // stable softplus
}

// ---------------- selective scan: chunk-parallel, s-in-registers, CH_R=16 ---
// Proven r6/r7/r8 algebra; chunks shrunk 64->16 rows for 4x grid parallelism
// (1024 blocks = 4 blocks/CU). E/L: (chunkg,d,s) -> ((chunkg*DI+d)*16+s).
__global__ __launch_bounds__(256)
void k_scanA(const float* __restrict__ dt, const float* __restrict__ proj,
             const unsigned short* __restrict__ xs, const float* __restrict__ Alog,
             float* __restrict__ Ebuf, float* __restrict__ Lbuf) {
  __shared__ float bp_lds[CH_R][DS];                // 1 KB
  const int bx = blockIdx.x;                        // 0..1023
  const int chunkg = bx >> 3;                       // 0..127
  const int d = (bx & 7) * 256 + threadIdx.x;       // 0..2047
  const int b = chunkg >> 6, c = chunkg & (NCH - 1);
  const int row0 = b * LEN + c * CH_R;
  {
    const int t = threadIdx.x;                      // 256 threads = 16x16 stage
    bp_lds[t >> 4][t & 15] = proj[(size_t)(row0 + (t >> 4)) * NPROJ + DS + (t & 15)];
  }
  __syncthreads();

  float a[DS], e[DS], L[DS];
#pragma unroll
  for (int s = 0; s < DS; ++s) {
    a[s] = -expf(Alog[d * DS + s]);
    e[s] = 1.f; L[s] = 0.f;
  }
#pragma unroll 4
  for (int j = 0; j < CH_R; ++j) {
    const size_t row = (size_t)(row0 + j);
    const float dtv = dt[row * DI + d];
    const float xv = bf16_f32(xs[row * DI + d]);
    const float u = dtv * xv;
#pragma unroll
    for (int q = 0; q < 4; ++q) {
      const float4 bq = *(const float4*)&bp_lds[j][q * 4];
      L[q * 4 + 0] += e[q * 4 + 0] * (u * bq.x);
      L[q * 4 + 1] += e[q * 4 + 1] * (u * bq.y);
      L[q * 4 + 2] += e[q * 4 + 2] * (u * bq.z);
      L[q * 4 + 3] += e[q * 4 + 3] * (u * bq.w);
    }
#pragma unroll
    for (int s = 0; s < DS; ++s)
      e[s] *= __expf(dtv * a[s]) + 1e-8f;
  }
  const size_t base = ((size_t)chunkg * DI + d) * DS;
#pragma unroll
  for (int q = 0; q < 4; ++q) {
    *(float4*)&Ebuf[base + q * 4] = make_float4(e[q*4], e[q*4+1], e[q*4+2], e[q*4+3]);
    *(float4*)&Lbuf[base + q * 4] = make_float4(L[q*4], L[q*4+1], L[q*4+2], L[q*4+3]);
  }
}

__global__ __launch_bounds__(256)
void k_scanB(float* __restrict__ Ebuf, float* __restrict__ Lbuf) {
  const int gid = blockIdx.x * 256 + threadIdx.x;   // b*32768 + d*16 + s
  const int s = gid & 15, d = (gid >> 4) & (DI - 1), b = gid >> 15;
  float scale = 1.f, H = 0.f;
  for (int c = 0; c < NCH; ++c) {
    const size_t idx = (((size_t)(b * NCH + c) * DI + d) << 4) + s;
    const float E = Ebuf[idx], Ls = Lbuf[idx];
    Ebuf[idx] = scale;                              // chunk-start scale
    Lbuf[idx] = H;                                  // chunk-start H
    H += scale * Ls;
    scale *= E;
  }
}

__global__ __launch_bounds__(256)
void k_scanC(const float* __restrict__ dt, const float* __restrict__ proj,
             const unsigned short* __restrict__ xs, const unsigned short* __restrict__ zb,
             const float* __restrict__ Alog, const float* __restrict__ Dp,
             const float* __restrict__ Ebuf, const float* __restrict__ Lbuf,
             unsigned short* __restrict__ v) {
  __shared__ float bp_lds[CH_R][DS];
  const int bx = blockIdx.x;
  const int chunkg = bx >> 3;
  const int d = (bx & 7) * 256 + threadIdx.x;
  const int b = chunkg >> 6, c = chunkg & (NCH - 1);
  const int row0 = b * LEN + c * CH_R;
  {
    const int t = threadIdx.x;
    bp_lds[t >> 4][t & 15] = proj[(size_t)(row0 + (t >> 4)) * NPROJ + DS + (t & 15)];
  }
  __syncthreads();

  const float Dd = Dp[d];
  float a[DS], e[DS], h[DS];
  const size_t base = ((size_t)chunkg * DI + d) * DS;
#pragma unroll
  for (int q = 0; q < 4; ++q) {
    const float4 ev = *(const float4*)&Ebuf[base + q * 4];
    const float4 hv = *(const float4*)&Lbuf[base + q * 4];
    e[q*4] = ev.x; e[q*4+1] = ev.y; e[q*4+2] = ev.z; e[q*4+3] = ev.w;
    h[q*4] = hv.x; h[q*4+1] = hv.y; h[q*4+2] = hv.z; h[q*4+3] = hv.w;
  }
#pragma unroll
  for (int s = 0; s < DS; ++s)
    a[s] = -expf(Alog[d * DS + s]);

#pragma unroll 4
  for (int j = 0; j < CH_R; ++j) {
    const size_t row = (size_t)(row0 + j);
    const float dtv = dt[row * DI + d];
    const float xv = bf16_f32(xs[row * DI + d]);
    const float u = dtv * xv;
#pragma unroll
    for (int q = 0; q < 4; ++q) {
      const float4 bq = *(const float4*)&bp_lds[j][q * 4];
      h[q * 4 + 0] += e[q * 4 + 0] * (u * bq.x);
      h[q * 4 + 1] += e[q * 4 + 1] * (u * bq.y);
      h[q * 4 + 2] += e[q * 4 + 2] * (u * bq.z);
      h[q * 4 + 3] += e[q * 4 + 3] * (u * bq.w);
    }
    float hs = 0.f;
#pragma unroll
    for (int s = 0; s < DS; ++s) hs += h[s];
    const float cp = proj[row * NPROJ + 2 * DS + d];
    const float z = bf16_f32(zb[row * DI + d]);
    const float y = cp * hs + xv * Dd;
    v[row * DI + d] = f32_bf16(y * (z / (1.f + __expf(-z))));
#pragma unroll
    for (int s = 0; s < DS; ++s)
      e[s] *= __expf(dtv * a[s]) + 1e-8f;
  }
}

extern "C" void kernel_launch(void* const* d_in, const int* in_sizes, int n_in,
                              void* d_out, int out_size, void* d_ws, size_t ws_size,
                              hipStream_t stream) {
  const float* x     = (const float*)d_in[0];
  const float* w_in  = (const float*)d_in[1];
  const float* b_in  = (const float*)d_in[2];
  const float* cw    = (const float*)d_in[3];
  const float* cb    = (const float*)d_in[4];
  const float* w_xp  = (const float*)d_in[5];
  const float* b_xp  = (const float*)d_in[6];
  const float* w_dt  = (const float*)d_in[7];
  const float* b_dt  = (const float*)d_in[8];
  const float* Alog  = (const float*)d_in[9];
  const float* Dp    = (const float*)d_in[10];
  const float* w_out = (const float*)d_in[11];
  const float* b_out = (const float*)d_in[12];
  float* out = (float*)d_out;

  // workspace layout, high-water 101,449,728 B (IDENTICAL to passing r8).
  // Lifetimes: w1t dead after gemm1; w2t dead after gemm2; dtb overlays
  // w1t+w2t (written post-gemm2); xbf dead after gemm1; xz dead after conv
  // (z compacted to zbf); Ebuf/Lbuf overlay xz EXACTLY (2x16,777,216 =
  // 33,554,432, written by scanA post-conv); xsb/zbf/proj live through scanC;
  // vb separate; w3t live till gemm3. d_out only written by gemm3.
  char* ws = (char*)d_ws;
  unsigned short* w1t = (unsigned short*)(ws);              //  8,388,608
  unsigned short* w2t = (unsigned short*)(ws + 8388608);    //  8,912,896
  unsigned short* w3t = (unsigned short*)(ws + 17301504);   //  4,194,304
  unsigned short* xbf = (unsigned short*)(ws + 21495808);   //  4,194,304
  float* xz   = (float*)(ws + 25690112);                    // 33,554,432
  unsigned short* xsb = (unsigned short*)(ws + 59244544);   //  8,388,608
  unsigned short* zbf = (unsigned short*)(ws + 67633152);   //  8,388,608 (FULL size)
  float* proj = (float*)(ws + 76021760);                    // 17,039,360 -> 93,061,120
  unsigned short* vb  = (unsigned short*)(ws + 93061120);   //  8,388,608 -> 101,449,728
  float* dtb  = (float*)(ws);                               // 16,777,216 overlay (w1t+w2t)
  float* Ebuf = (float*)(ws + 25690112);                    // 16,777,216 overlay (xz lo)
  float* Lbuf = (float*)(ws + 42467328);                    // 16,777,216 overlay (xz hi)

  const dim3 blk(256);
  // weight transpose + bf16 cast
  k_transpose_bf16<<<dim3(4096 / 32, 1024 / 32), blk, 0, stream>>>(w_in, w1t, 1024, 4096);
  k_transpose_bf16<<<dim3(NPROJ_PAD / 32, 2048 / 32), blk, 0, stream>>>(w_xp, w2t, 2048, NPROJ);
  k_transpose_bf16<<<dim3(1024 / 32, 2048 / 32), blk, 0, stream>>>(w_out, w3t, 2048, 1024);
  k_cast_bf16<<<dim3(NROWS * DM / (256 * 8)), blk, 0, stream>>>(x, xbf);
  // xz = x @ in_proj_w + b
  k_gemm_bf<<<dim3(4096 / 128, 2048 / 128), blk, 0, stream>>>(xbf, 1024, w1t, 1024, b_in, xz, 4096, 1024, 4096);
  // xs = silu(causal_dwconv(xc)) [bf16]; z compacted [bf16]
  k_conv_silu_z<<<dim3(NROWS * DI / 256), blk, 0, stream>>>(xz, cw, cb, xsb, zbf);
  // proj = xs @ x_proj_w + b
  k_gemm_bf<<<dim3(NPROJ_PAD / 128, 2048 / 128), blk, 0, stream>>>(xsb, 2048, w2t, 2048, b_xp, proj, NPROJ, 2048, NPROJ);
  // dt = softplus(proj[:, :16] @ dt_proj_w + b)
  k_dtproj<<<dim3(NROWS * DI / 256), blk, 0, stream>>>(proj, w_dt, b_dt, dtb);
  // selective scan (chunk-parallel CH_R=16) + gate -> v (bf16)
  k_scanA<<<dim3(TOTCH * 8), blk, 0, stream>>>(dtb, proj, xsb, Alog, Ebuf, Lbuf);
  k_scanB<<<dim3(NB * DI * DS / 256), blk, 0, stream>>>(Ebuf, Lbuf);
  k_scanC<<<dim3(TOTCH * 8), blk, 0, stream>>>(dtb, proj, xsb, zbf, Alog, Dp, Ebuf, Lbuf, vb);
  // out = v @ out_proj_w + b
  k_gemm_bf<<<dim3(1024 / 128, 2048 / 128), blk, 0, stream>>>(vb, 2048, w3t, 2048, b_out, out, 1024, 2048, 1024);
}

// Round 10
// 343.787 us; speedup vs baseline: 1.5361x; 1.0062x over previous
//
#include <hip/hip_runtime.h>

#define DI 2048
#define DM 1024
#define DS 16
#define LEN 1024
#define NB 2
#define NROWS (NB * LEN)        // 2048
#define NPROJ (2 * DS + DI)     // 2080
#define NPROJ_PAD 2176
#define N_XZ (2 * DI)           // 4096
#define CH_R 16                 // rows per scan chunk
#define NCH (LEN / CH_R)        // 64 chunks per batch
#define TOTCH (NB * NCH)        // 128 chunks total

using bf16x8 = __attribute__((ext_vector_type(8))) short;
using f32x4  = __attribute__((ext_vector_type(4))) float;

__device__ __forceinline__ unsigned short f32_bf16(float f) {
  unsigned int u = __float_as_uint(f);
  u += 0x7fffu + ((u >> 16) & 1u);   // round-to-nearest-even
  return (unsigned short)(u >> 16);
}
__device__ __forceinline__ float bf16_f32(unsigned short h) {
  return __uint_as_float((unsigned int)h << 16);
}

// ---------------- transpose + cast: W (K x N) f32 -> Wt (Npad x K) bf16 -----
__global__ __launch_bounds__(256)
void k_transpose_bf16(const float* __restrict__ W, unsigned short* __restrict__ Wt,
                      int K, int N) {
  __shared__ float tile[32][33];
  const int n0 = blockIdx.x * 32, k0 = blockIdx.y * 32;
  const int tx = threadIdx.x & 31;
  const int ty = threadIdx.x >> 5;
#pragma unroll
  for (int j = 0; j < 32; j += 8) {
    const int n = n0 + tx, k = k0 + ty + j;
    tile[ty + j][tx] = (n < N) ? W[(size_t)k * N + n] : 0.f;  // pad rows -> 0
  }
  __syncthreads();
#pragma unroll
  for (int j = 0; j < 32; j += 8)
    Wt[(size_t)(n0 + ty + j) * K + (k0 + tx)] = f32_bf16(tile[tx][ty + j]);
}

// ---------------- elementwise cast f32 -> bf16 (8/thread) -------------------
__global__ __launch_bounds__(256)
void k_cast_bf16(const float* __restrict__ in, unsigned short* __restrict__ out) {
  const int i8 = (blockIdx.x * 256 + threadIdx.x) * 8;
  const float4 a = *(const float4*)(in + i8);
  const float4 b = *(const float4*)(in + i8 + 4);
  ushort4 lo, hi;
  lo.x = f32_bf16(a.x); lo.y = f32_bf16(a.y); lo.z = f32_bf16(a.z); lo.w = f32_bf16(a.w);
  hi.x = f32_bf16(b.x); hi.y = f32_bf16(b.y); hi.z = f32_bf16(b.z); hi.w = f32_bf16(b.w);
  *(ushort4*)(out + i8) = lo;
  *(ushort4*)(out + i8 + 4) = hi;
}

// ---------------- bf16 MFMA GEMM, 8 waves, double-buffered K-loop -----------
// r9's proven dbuf/staging structure, re-decomposed: 512 threads (8 waves),
// each wave owns 32x64 of the 128x128 tile (acc 2x4). Each thread stages ONE
// uint4 per operand. LDS layout (stride 40) and global pattern unchanged.
__global__ __launch_bounds__(512)
void k_gemm_bf(const unsigned short* __restrict__ A, int lda,
               const unsigned short* __restrict__ Bt, int ldb,
               const float* __restrict__ bias,
               float* __restrict__ C, int ldc,
               int K, int Nlog) {
  __shared__ __align__(16) unsigned short As[2][128 * 40];  // 2 x 10240 B
  __shared__ __align__(16) unsigned short Bs[2][128 * 40];
  const int tid = threadIdx.x;
  const int m0 = blockIdx.y * 128;
  const int n0 = blockIdx.x * 128;
  const int lane = tid & 63;
  const int wid = tid >> 6;               // 0..7
  const int wr = (wid >> 1) * 32;         // 0,32,64,96
  const int wc = (wid & 1) * 64;          // 0,64
  const int g = lane >> 4, r = lane & 15;

  const int srow = tid >> 2;              // 0..127
  const int scol = (tid & 3) * 8;         // 0,8,16,24

  const unsigned short* Ap = A + (size_t)(m0 + srow) * lda + scol;
  const unsigned short* Bp = Bt + (size_t)(n0 + srow) * ldb + scol;
  const int swoff = srow * 40 + scol;

  f32x4 acc[2][4] = {};
  uint4 ra, rb;

#define LOADG(k0) do {                                                        \
    ra = *(const uint4*)(Ap + (k0));                                          \
    rb = *(const uint4*)(Bp + (k0));                                          \
  } while (0)

#define STORE(bf) do {                                                        \
    *(uint4*)&As[bf][swoff] = ra;                                             \
    *(uint4*)&Bs[bf][swoff] = rb;                                             \
  } while (0)

#define COMPUTE(bf) do {                                                      \
    bf16x8 af[2], bfr[4];                                                     \
    _Pragma("unroll")                                                         \
    for (int i = 0; i < 2; ++i)                                               \
      af[i] = *(const bf16x8*)&As[bf][(wr + i * 16 + r) * 40 + 8 * g];        \
    _Pragma("unroll")                                                         \
    for (int j = 0; j < 4; ++j)                                               \
      bfr[j] = *(const bf16x8*)&Bs[bf][(wc + j * 16 + r) * 40 + 8 * g];       \
    _Pragma("unroll")                                                         \
    for (int i = 0; i < 2; ++i)                                               \
      _Pragma("unroll")                                                       \
      for (int j = 0; j < 4; ++j)                                             \
        acc[i][j] = __builtin_amdgcn_mfma_f32_16x16x32_bf16(af[i], bfr[j],    \
                                                            acc[i][j], 0, 0, 0);\
  } while (0)

  LOADG(0);
  STORE(0);
  __syncthreads();
  int buf = 0;
  for (int k0 = 32; k0 < K; k0 += 32) {
    LOADG(k0);          // prefetch next tile (latency hides under COMPUTE)
    COMPUTE(buf);
    STORE(buf ^ 1);     // write other buffer; current readers unaffected
    __syncthreads();    // one barrier per k-step
    buf ^= 1;
  }
  COMPUTE(buf);

#undef LOADG
#undef STORE
#undef COMPUTE

#pragma unroll
  for (int i = 0; i < 2; ++i) {
    const int row = m0 + wr + i * 16 + 4 * g;  // C/D: row=(lane>>4)*4+reg
#pragma unroll
    for (int j = 0; j < 4; ++j) {
      const int col = n0 + wc + j * 16 + r;    // C/D: col=lane&15
      if (col < Nlog) {
        const float bv = bias[col];
#pragma unroll
        for (int q = 0; q < 4; ++q)
          C[(size_t)(row + q) * ldc + col] = acc[i][j][q] + bv;
      }
    }
  }
}

// ---------------- causal depthwise conv (k=4) + silu -> bf16 xs; compact z --
__global__ __launch_bounds__(256)
void k_conv_silu_z(const float* __restrict__ xz, const float* __restrict__ cw,
                   const float* __restrict__ cb,
                   unsigned short* __restrict__ xs, unsigned short* __restrict__ zb) {
  const int idx = blockIdx.x * 256 + threadIdx.x;   // row*DI + d
  const int d = idx & (DI - 1);
  const int row = idx >> 11;
  const int l = row & (LEN - 1);
  const float w0 = cw[d * 4], w1 = cw[d * 4 + 1], w2 = cw[d * 4 + 2], w3 = cw[d * 4 + 3];
  const float* p = xz + (size_t)row * N_XZ + d;     // xc = first DI cols of xz
  float acc = cb[d] + w3 * p[0];
  if (l >= 1) acc += w2 * p[-N_XZ];
  if (l >= 2) acc += w1 * p[-2 * N_XZ];
  if (l >= 3) acc += w0 * p[-3 * N_XZ];
  xs[idx] = f32_bf16(acc / (1.f + expf(-acc)));     // silu, bf16
  zb[idx] = f32_bf16(p[DI]);                        // z = xz[row, DI + d]
}

// ---------------- dt = softplus(proj[:, :16] @ dt_proj_w + b) (unchanged) ---
__global__ __launch_bounds__(256)
void k_dtproj(const float* __restrict__ proj, const float* __restrict__ w,
              const float* __restrict__ b, float* __restrict__ dt) {
  const int idx = blockIdx.x * 256 + threadIdx.x;
  const int d = idx & (DI - 1);
  const int row = idx >> 11;
  const float* p = proj + (size_t)row * NPROJ;
  float acc = b[d];
#pragma unroll
  for (int s = 0; s < DS; ++s) acc += p[s] * w[s * DI + d];
  dt[idx] = fmaxf(acc, 0.f) + log1pf(expf(-fabsf(acc)));  // stable softplus
}

// ---------------- selective scan: chunk-parallel, s-in-registers, CH_R=16 ---
__global__ __launch_bounds__(256)
void k_scanA(const float* __restrict__ dt, const float* __restrict__ proj,
             const unsigned short* __restrict__ xs, const float* __restrict__ Alog,
             float* __restrict__ Ebuf, float* __restrict__ Lbuf) {
  __shared__ float bp_lds[CH_R][DS];                // 1 KB
  const int bx = blockIdx.x;                        // 0..1023
  const int chunkg = bx >> 3;                       // 0..127
  const int d = (bx & 7) * 256 + threadIdx.x;       // 0..2047
  const int b = chunkg >> 6, c = chunkg & (NCH - 1);
  const int row0 = b * LEN + c * CH_R;
  {
    const int t = threadIdx.x;                      // 256 threads = 16x16 stage
    bp_lds[t >> 4][t & 15] = proj[(size_t)(row0 + (t >> 4)) * NPROJ + DS + (t & 15)];
  }
  __syncthreads();

  float a[DS], e[DS], L[DS];
#pragma unroll
  for (int s = 0; s < DS; ++s) {
    a[s] = -expf(Alog[d * DS + s]);
    e[s] = 1.f; L[s] = 0.f;
  }
#pragma unroll 4
  for (int j = 0; j < CH_R; ++j) {
    const size_t row = (size_t)(row0 + j);
    const float dtv = dt[row * DI + d];
    const float xv = bf16_f32(xs[row * DI + d]);
    const float u = dtv * xv;
#pragma unroll
    for (int q = 0; q < 4; ++q) {
      const float4 bq = *(const float4*)&bp_lds[j][q * 4];
      L[q * 4 + 0] += e[q * 4 + 0] * (u * bq.x);
      L[q * 4 + 1] += e[q * 4 + 1] * (u * bq.y);
      L[q * 4 + 2] += e[q * 4 + 2] * (u * bq.z);
      L[q * 4 + 3] += e[q * 4 + 3] * (u * bq.w);
    }
#pragma unroll
    for (int s = 0; s < DS; ++s)
      e[s] *= __expf(dtv * a[s]) + 1e-8f;
  }
  const size_t base = ((size_t)chunkg * DI + d) * DS;
#pragma unroll
  for (int q = 0; q < 4; ++q) {
    *(float4*)&Ebuf[base + q * 4] = make_float4(e[q*4], e[q*4+1], e[q*4+2], e[q*4+3]);
    *(float4*)&Lbuf[base + q * 4] = make_float4(L[q*4], L[q*4+1], L[q*4+2], L[q*4+3]);
  }
}

__global__ __launch_bounds__(256)
void k_scanB(float* __restrict__ Ebuf, float* __restrict__ Lbuf) {
  const int gid = blockIdx.x * 256 + threadIdx.x;   // b*32768 + d*16 + s
  const int s = gid & 15, d = (gid >> 4) & (DI - 1), b = gid >> 15;
  float scale = 1.f, H = 0.f;
  for (int c = 0; c < NCH; ++c) {
    const size_t idx = (((size_t)(b * NCH + c) * DI + d) << 4) + s;
    const float E = Ebuf[idx], Ls = Lbuf[idx];
    Ebuf[idx] = scale;                              // chunk-start scale
    Lbuf[idx] = H;                                  // chunk-start H
    H += scale * Ls;
    scale *= E;
  }
}

__global__ __launch_bounds__(256)
void k_scanC(const float* __restrict__ dt, const float* __restrict__ proj,
             const unsigned short* __restrict__ xs, const unsigned short* __restrict__ zb,
             const float* __restrict__ Alog, const float* __restrict__ Dp,
             const float* __restrict__ Ebuf, const float* __restrict__ Lbuf,
             unsigned short* __restrict__ v) {
  __shared__ float bp_lds[CH_R][DS];
  const int bx = blockIdx.x;
  const int chunkg = bx >> 3;
  const int d = (bx & 7) * 256 + threadIdx.x;
  const int b = chunkg >> 6, c = chunkg & (NCH - 1);
  const int row0 = b * LEN + c * CH_R;
  {
    const int t = threadIdx.x;
    bp_lds[t >> 4][t & 15] = proj[(size_t)(row0 + (t >> 4)) * NPROJ + DS + (t & 15)];
  }
  __syncthreads();

  const float Dd = Dp[d];
  float a[DS], e[DS], h[DS];
  const size_t base = ((size_t)chunkg * DI + d) * DS;
#pragma unroll
  for (int q = 0; q < 4; ++q) {
    const float4 ev = *(const float4*)&Ebuf[base + q * 4];
    const float4 hv = *(const float4*)&Lbuf[base + q * 4];
    e[q*4] = ev.x; e[q*4+1] = ev.y; e[q*4+2] = ev.z; e[q*4+3] = ev.w;
    h[q*4] = hv.x; h[q*4+1] = hv.y; h[q*4+2] = hv.z; h[q*4+3] = hv.w;
  }
#pragma unroll
  for (int s = 0; s < DS; ++s)
    a[s] = -expf(Alog[d * DS + s]);

#pragma unroll 4
  for (int j = 0; j < CH_R; ++j) {
    const size_t row = (size_t)(row0 + j);
    const float dtv = dt[row * DI + d];
    const float xv = bf16_f32(xs[row * DI + d]);
    const float u = dtv * xv;
#pragma unroll
    for (int q = 0; q < 4; ++q) {
      const float4 bq = *(const float4*)&bp_lds[j][q * 4];
      h[q * 4 + 0] += e[q * 4 + 0] * (u * bq.x);
      h[q * 4 + 1] += e[q * 4 + 1] * (u * bq.y);
      h[q * 4 + 2] += e[q * 4 + 2] * (u * bq.z);
      h[q * 4 + 3] += e[q * 4 + 3] * (u * bq.w);
    }
    float hs = 0.f;
#pragma unroll
    for (int s = 0; s < DS; ++s) hs += h[s];
    const float cp = proj[row * NPROJ + 2 * DS + d];
    const float z = bf16_f32(zb[row * DI + d]);
    const float y = cp * hs + xv * Dd;
    v[row * DI + d] = f32_bf16(y * (z / (1.f + __expf(-z))));
#pragma unroll
    for (int s = 0; s < DS; ++s)
      e[s] *= __expf(dtv * a[s]) + 1e-8f;
  }
}

extern "C" void kernel_launch(void* const* d_in, const int* in_sizes, int n_in,
                              void* d_out, int out_size, void* d_ws, size_t ws_size,
                              hipStream_t stream) {
  const float* x     = (const float*)d_in[0];
  const float* w_in  = (const float*)d_in[1];
  const float* b_in  = (const float*)d_in[2];
  const float* cw    = (const float*)d_in[3];
  const float* cb    = (const float*)d_in[4];
  const float* w_xp  = (const float*)d_in[5];
  const float* b_xp  = (const float*)d_in[6];
  const float* w_dt  = (const float*)d_in[7];
  const float* b_dt  = (const float*)d_in[8];
  const float* Alog  = (const float*)d_in[9];
  const float* Dp    = (const float*)d_in[10];
  const float* w_out = (const float*)d_in[11];
  const float* b_out = (const float*)d_in[12];
  float* out = (float*)d_out;

  // workspace layout, high-water 101,449,728 B (IDENTICAL to passing r8/r9).
  char* ws = (char*)d_ws;
  unsigned short* w1t = (unsigned short*)(ws);              //  8,388,608
  unsigned short* w2t = (unsigned short*)(ws + 8388608);    //  8,912,896
  unsigned short* w3t = (unsigned short*)(ws + 17301504);   //  4,194,304
  unsigned short* xbf = (unsigned short*)(ws + 21495808);   //  4,194,304
  float* xz   = (float*)(ws + 25690112);                    // 33,554,432
  unsigned short* xsb = (unsigned short*)(ws + 59244544);   //  8,388,608
  unsigned short* zbf = (unsigned short*)(ws + 67633152);   //  8,388,608 (FULL size)
  float* proj = (float*)(ws + 76021760);                    // 17,039,360 -> 93,061,120
  unsigned short* vb  = (unsigned short*)(ws + 93061120);   //  8,388,608 -> 101,449,728
  float* dtb  = (float*)(ws);                               // 16,777,216 overlay (w1t+w2t)
  float* Ebuf = (float*)(ws + 25690112);                    // 16,777,216 overlay (xz lo)
  float* Lbuf = (float*)(ws + 42467328);                    // 16,777,216 overlay (xz hi)

  const dim3 blk(256);
  const dim3 blkg(512);
  // weight transpose + bf16 cast
  k_transpose_bf16<<<dim3(4096 / 32, 1024 / 32), blk, 0, stream>>>(w_in, w1t, 1024, 4096);
  k_transpose_bf16<<<dim3(NPROJ_PAD / 32, 2048 / 32), blk, 0, stream>>>(w_xp, w2t, 2048, NPROJ);
  k_transpose_bf16<<<dim3(1024 / 32, 2048 / 32), blk, 0, stream>>>(w_out, w3t, 2048, 1024);
  k_cast_bf16<<<dim3(NROWS * DM / (256 * 8)), blk, 0, stream>>>(x, xbf);
  // xz = x @ in_proj_w + b
  k_gemm_bf<<<dim3(4096 / 128, 2048 / 128), blkg, 0, stream>>>(xbf, 1024, w1t, 1024, b_in, xz, 4096, 1024, 4096);
  // xs = silu(causal_dwconv(xc)) [bf16]; z compacted [bf16]
  k_conv_silu_z<<<dim3(NROWS * DI / 256), blk, 0, stream>>>(xz, cw, cb, xsb, zbf);
  // proj = xs @ x_proj_w + b
  k_gemm_bf<<<dim3(NPROJ_PAD / 128, 2048 / 128), blkg, 0, stream>>>(xsb, 2048, w2t, 2048, b_xp, proj, NPROJ, 2048, NPROJ);
  // dt = softplus(proj[:, :16] @ dt_proj_w + b)
  k_dtproj<<<dim3(NROWS * DI / 256), blk, 0, stream>>>(proj, w_dt, b_dt, dtb);
  // selective scan (chunk-parallel CH_R=16) + gate -> v (bf16)
  k_scanA<<<dim3(TOTCH * 8), blk, 0, stream>>>(dtb, proj, xsb, Alog, Ebuf, Lbuf);
  k_scanB<<<dim3(NB * DI * DS / 256), blk, 0, stream>>>(Ebuf, Lbuf);
  k_scanC<<<dim3(TOTCH * 8), blk, 0, stream>>>(dtb, proj, xsb, zbf, Alog, Dp, Ebuf, Lbuf, vb);
  // out = v @ out_proj_w + b
  k_gemm_bf<<<dim3(1024 / 128, 2048 / 128), blkg, 0, stream>>>(vb, 2048, w3t, 2048, b_out, out, 1024, 2048, 1024);
}

// Round 11
// 337.391 us; speedup vs baseline: 1.5653x; 1.0190x over previous
//
#include <hip/hip_runtime.h>

#define DI 2048
#define DM 1024
#define DS 16
#define LEN 1024
#define NB 2
#define NROWS (NB * LEN)        // 2048
#define NPROJ (2 * DS + DI)     // 2080
#define NPROJ_PAD 2176
#define N_XZ (2 * DI)           // 4096
#define CH_R 16                 // rows per scan chunk
#define NCH (LEN / CH_R)        // 64 chunks per batch
#define TOTCH (NB * NCH)        // 128 chunks total

using bf16x8 = __attribute__((ext_vector_type(8))) short;
using f32x4  = __attribute__((ext_vector_type(4))) float;

__device__ __forceinline__ unsigned short f32_bf16(float f) {
  unsigned int u = __float_as_uint(f);
  u += 0x7fffu + ((u >> 16) & 1u);   // round-to-nearest-even
  return (unsigned short)(u >> 16);
}
__device__ __forceinline__ float bf16_f32(unsigned short h) {
  return __uint_as_float((unsigned int)h << 16);
}

// ---------------- fused prep: 3 weight transposes + x cast ------------------
// job0: w_in  (K=1024,N=4096) -> w1t   blocks [0,4096)
// job1: w_xp  (K=2048,N=2080,pad 2176) -> w2t  blocks [4096,8448)
// job2: w_out (K=2048,N=1024) -> w3t   blocks [8448,10496)
// job3: cast x -> xbf                  blocks [10496,11520)
__device__ __forceinline__ void transpose_tile(const float* __restrict__ W,
                                               unsigned short* __restrict__ Wt,
                                               int K, int N, int bx, int by,
                                               int tid, float (*tile)[33]) {
  const int n0 = bx * 32, k0 = by * 32;
  const int tx = tid & 31, ty = tid >> 5;
#pragma unroll
  for (int j = 0; j < 32; j += 8) {
    const int n = n0 + tx;
    tile[ty + j][tx] = (n < N) ? W[(size_t)(k0 + ty + j) * N + n] : 0.f;
  }
  __syncthreads();
#pragma unroll
  for (int j = 0; j < 32; j += 8)
    Wt[(size_t)(n0 + ty + j) * K + (k0 + tx)] = f32_bf16(tile[tx][ty + j]);
}

__global__ __launch_bounds__(256)
void k_prep(const float* __restrict__ w_in, const float* __restrict__ w_xp,
            const float* __restrict__ w_out, const float* __restrict__ x,
            unsigned short* __restrict__ w1t, unsigned short* __restrict__ w2t,
            unsigned short* __restrict__ w3t, unsigned short* __restrict__ xbf) {
  __shared__ float tile[32][33];
  const int bid = blockIdx.x;
  const int tid = threadIdx.x;
  if (bid < 4096) {
    transpose_tile(w_in, w1t, 1024, 4096, bid % 128, bid / 128, tid, tile);
  } else if (bid < 8448) {
    const int b = bid - 4096;
    transpose_tile(w_xp, w2t, 2048, NPROJ, b % 68, b / 68, tid, tile);
  } else if (bid < 10496) {
    const int b = bid - 8448;
    transpose_tile(w_out, w3t, 2048, 1024, b % 32, b / 32, tid, tile);
  } else {
    const int b = bid - 10496;
    const int i8 = (b * 256 + tid) * 8;
    const float4 a = *(const float4*)(x + i8);
    const float4 c = *(const float4*)(x + i8 + 4);
    ushort4 lo, hi;
    lo.x = f32_bf16(a.x); lo.y = f32_bf16(a.y); lo.z = f32_bf16(a.z); lo.w = f32_bf16(a.w);
    hi.x = f32_bf16(c.x); hi.y = f32_bf16(c.y); hi.z = f32_bf16(c.z); hi.w = f32_bf16(c.w);
    *(ushort4*)(xbf + i8) = lo;
    *(ushort4*)(xbf + i8 + 4) = hi;
  }
}

// ---------------- bf16 MFMA GEMM, 8 waves, dbuf K-loop (r10 passing) --------
// OUTBF=1: C written as bf16 (ushort); else f32.
template <int OUTBF>
__global__ __launch_bounds__(512)
void k_gemm_bf(const unsigned short* __restrict__ A, int lda,
               const unsigned short* __restrict__ Bt, int ldb,
               const float* __restrict__ bias,
               void* __restrict__ Cv, int ldc,
               int K, int Nlog) {
  __shared__ __align__(16) unsigned short As[2][128 * 40];  // 2 x 10240 B
  __shared__ __align__(16) unsigned short Bs[2][128 * 40];
  const int tid = threadIdx.x;
  const int m0 = blockIdx.y * 128;
  const int n0 = blockIdx.x * 128;
  const int lane = tid & 63;
  const int wid = tid >> 6;               // 0..7
  const int wr = (wid >> 1) * 32;         // 0,32,64,96
  const int wc = (wid & 1) * 64;          // 0,64
  const int g = lane >> 4, r = lane & 15;

  const int srow = tid >> 2;              // 0..127
  const int scol = (tid & 3) * 8;         // 0,8,16,24

  const unsigned short* Ap = A + (size_t)(m0 + srow) * lda + scol;
  const unsigned short* Bp = Bt + (size_t)(n0 + srow) * ldb + scol;
  const int swoff = srow * 40 + scol;

  f32x4 acc[2][4] = {};
  uint4 ra, rb;

#define LOADG(k0) do {                                                        \
    ra = *(const uint4*)(Ap + (k0));                                          \
    rb = *(const uint4*)(Bp + (k0));                                          \
  } while (0)

#define STORE(bf) do {                                                        \
    *(uint4*)&As[bf][swoff] = ra;                                             \
    *(uint4*)&Bs[bf][swoff] = rb;                                             \
  } while (0)

#define COMPUTE(bf) do {                                                      \
    bf16x8 af[2], bfr[4];                                                     \
    _Pragma("unroll")                                                         \
    for (int i = 0; i < 2; ++i)                                               \
      af[i] = *(const bf16x8*)&As[bf][(wr + i * 16 + r) * 40 + 8 * g];        \
    _Pragma("unroll")                                                         \
    for (int j = 0; j < 4; ++j)                                               \
      bfr[j] = *(const bf16x8*)&Bs[bf][(wc + j * 16 + r) * 40 + 8 * g];       \
    _Pragma("unroll")                                                         \
    for (int i = 0; i < 2; ++i)                                               \
      _Pragma("unroll")                                                       \
      for (int j = 0; j < 4; ++j)                                             \
        acc[i][j] = __builtin_amdgcn_mfma_f32_16x16x32_bf16(af[i], bfr[j],    \
                                                            acc[i][j], 0, 0, 0);\
  } while (0)

  LOADG(0);
  STORE(0);
  __syncthreads();
  int buf = 0;
  for (int k0 = 32; k0 < K; k0 += 32) {
    LOADG(k0);          // prefetch next tile (latency hides under COMPUTE)
    COMPUTE(buf);
    STORE(buf ^ 1);     // write other buffer; current readers unaffected
    __syncthreads();    // one barrier per k-step
    buf ^= 1;
  }
  COMPUTE(buf);

#undef LOADG
#undef STORE
#undef COMPUTE

#pragma unroll
  for (int i = 0; i < 2; ++i) {
    const int row = m0 + wr + i * 16 + 4 * g;  // C/D: row=(lane>>4)*4+reg
#pragma unroll
    for (int j = 0; j < 4; ++j) {
      const int col = n0 + wc + j * 16 + r;    // C/D: col=lane&15
      if (col < Nlog) {
        const float bv = bias[col];
        if (OUTBF) {
          unsigned short* C = (unsigned short*)Cv;
#pragma unroll
          for (int q = 0; q < 4; ++q)
            C[(size_t)(row + q) * ldc + col] = f32_bf16(acc[i][j][q] + bv);
        } else {
          float* C = (float*)Cv;
#pragma unroll
          for (int q = 0; q < 4; ++q)
            C[(size_t)(row + q) * ldc + col] = acc[i][j][q] + bv;
        }
      }
    }
  }
}

// ---------------- causal depthwise conv (k=4) + silu, bf16 in/out -----------
__global__ __launch_bounds__(256)
void k_conv_silu(const unsigned short* __restrict__ xzb, const float* __restrict__ cw,
                 const float* __restrict__ cb, unsigned short* __restrict__ xs) {
  const int idx = blockIdx.x * 256 + threadIdx.x;   // row*DI + d
  const int d = idx & (DI - 1);
  const int row = idx >> 11;
  const int l = row & (LEN - 1);
  const float w0 = cw[d * 4], w1 = cw[d * 4 + 1], w2 = cw[d * 4 + 2], w3 = cw[d * 4 + 3];
  const unsigned short* p = xzb + (size_t)row * N_XZ + d;   // xc cols of xz
  float acc = cb[d] + w3 * bf16_f32(p[0]);
  if (l >= 1) acc += w2 * bf16_f32(p[-N_XZ]);
  if (l >= 2) acc += w1 * bf16_f32(p[-2 * N_XZ]);
  if (l >= 3) acc += w0 * bf16_f32(p[-3 * N_XZ]);
  xs[idx] = f32_bf16(acc / (1.f + expf(-acc)));     // silu, bf16
}

// ---------------- selective scan, dt fused (recomputed from proj) -----------
// dt = softplus(b_dt[d] + sum_s proj[row,s] * w_dt[s,d]) — identical
// accumulation order to the old k_dtproj. Wdt block-slice staged in LDS.
__global__ __launch_bounds__(256)
void k_scanA(const float* __restrict__ proj, const unsigned short* __restrict__ xs,
             const float* __restrict__ Alog, const float* __restrict__ w_dt,
             const float* __restrict__ b_dt,
             float* __restrict__ Ebuf, float* __restrict__ Lbuf) {
  __shared__ float bp_lds[CH_R][DS];                // 1 KB
  __shared__ float dtp_lds[CH_R][DS];               // 1 KB
  __shared__ float wdt_lds[DS][256];                // 16 KB
  const int bx = blockIdx.x;                        // 0..1023
  const int chunkg = bx >> 3;                       // 0..127
  const int t = threadIdx.x;
  const int d = (bx & 7) * 256 + t;                 // 0..2047
  const int b = chunkg >> 6, c = chunkg & (NCH - 1);
  const int row0 = b * LEN + c * CH_R;
  bp_lds[t >> 4][t & 15] = proj[(size_t)(row0 + (t >> 4)) * NPROJ + DS + (t & 15)];
  dtp_lds[t >> 4][t & 15] = proj[(size_t)(row0 + (t >> 4)) * NPROJ + (t & 15)];
#pragma unroll
  for (int s = 0; s < DS; ++s)
    wdt_lds[s][t] = w_dt[s * DI + d];
  __syncthreads();

  const float bdt = b_dt[d];
  float a[DS], e[DS], L[DS];
#pragma unroll
  for (int s = 0; s < DS; ++s) {
    a[s] = -expf(Alog[d * DS + s]);
    e[s] = 1.f; L[s] = 0.f;
  }
#pragma unroll 4
  for (int j = 0; j < CH_R; ++j) {
    const size_t row = (size_t)(row0 + j);
    float pre = bdt;
#pragma unroll
    for (int s = 0; s < DS; ++s)
      pre += dtp_lds[j][s] * wdt_lds[s][t];
    const float dtv = fmaxf(pre, 0.f) + log1pf(expf(-fabsf(pre)));  // softplus
    const float xv = bf16_f32(xs[row * DI + d]);
    const float u = dtv * xv;
#pragma unroll
    for (int q = 0; q < 4; ++q) {
      const float4 bq = *(const float4*)&bp_lds[j][q * 4];
      L[q * 4 + 0] += e[q * 4 + 0] * (u * bq.x);
      L[q * 4 + 1] += e[q * 4 + 1] * (u * bq.y);
      L[q * 4 + 2] += e[q * 4 + 2] * (u * bq.z);
      L[q * 4 + 3] += e[q * 4 + 3] * (u * bq.w);
    }
#pragma unroll
    for (int s = 0; s < DS; ++s)
      e[s] *= __expf(dtv * a[s]) + 1e-8f;
  }
  const size_t base = ((size_t)chunkg * DI + d) * DS;
#pragma unroll
  for (int q = 0; q < 4; ++q) {
    *(float4*)&Ebuf[base + q * 4] = make_float4(e[q*4], e[q*4+1], e[q*4+2], e[q*4+3]);
    *(float4*)&Lbuf[base + q * 4] = make_float4(L[q*4], L[q*4+1], L[q*4+2], L[q*4+3]);
  }
}

__global__ __launch_bounds__(256)
void k_scanB(float* __restrict__ Ebuf, float* __restrict__ Lbuf) {
  const int gid = blockIdx.x * 256 + threadIdx.x;   // b*32768 + d*16 + s
  const int s = gid & 15, d = (gid >> 4) & (DI - 1), b = gid >> 15;
  float scale = 1.f, H = 0.f;
  for (int c = 0; c < NCH; ++c) {
    const size_t idx = (((size_t)(b * NCH + c) * DI + d) << 4) + s;
    const float E = Ebuf[idx], Ls = Lbuf[idx];
    Ebuf[idx] = scale;                              // chunk-start scale
    Lbuf[idx] = H;                                  // chunk-start H
    H += scale * Ls;
    scale *= E;
  }
}

__global__ __launch_bounds__(256)
void k_scanC(const float* __restrict__ proj, const unsigned short* __restrict__ xs,
             const unsigned short* __restrict__ xzb,
             const float* __restrict__ Alog, const float* __restrict__ Dp,
             const float* __restrict__ w_dt, const float* __restrict__ b_dt,
             const float* __restrict__ Ebuf, const float* __restrict__ Lbuf,
             unsigned short* __restrict__ v) {
  __shared__ float bp_lds[CH_R][DS];
  __shared__ float dtp_lds[CH_R][DS];
  __shared__ float wdt_lds[DS][256];
  const int bx = blockIdx.x;
  const int chunkg = bx >> 3;
  const int t = threadIdx.x;
  const int d = (bx & 7) * 256 + t;
  const int b = chunkg >> 6, c = chunkg & (NCH - 1);
  const int row0 = b * LEN + c * CH_R;
  bp_lds[t >> 4][t & 15] = proj[(size_t)(row0 + (t >> 4)) * NPROJ + DS + (t & 15)];
  dtp_lds[t >> 4][t & 15] = proj[(size_t)(row0 + (t >> 4)) * NPROJ + (t & 15)];
#pragma unroll
  for (int s = 0; s < DS; ++s)
    wdt_lds[s][t] = w_dt[s * DI + d];
  __syncthreads();

  const float bdt = b_dt[d];
  const float Dd = Dp[d];
  float a[DS], e[DS], h[DS];
  const size_t base = ((size_t)chunkg * DI + d) * DS;
#pragma unroll
  for (int q = 0; q < 4; ++q) {
    const float4 ev = *(const float4*)&Ebuf[base + q * 4];
    const float4 hv = *(const float4*)&Lbuf[base + q * 4];
    e[q*4] = ev.x; e[q*4+1] = ev.y; e[q*4+2] = ev.z; e[q*4+3] = ev.w;
    h[q*4] = hv.x; h[q*4+1] = hv.y; h[q*4+2] = hv.z; h[q*4+3] = hv.w;
  }
#pragma unroll
  for (int s = 0; s < DS; ++s)
    a[s] = -expf(Alog[d * DS + s]);

#pragma unroll 4
  for (int j = 0; j < CH_R; ++j) {
    const size_t row = (size_t)(row0 + j);
    float pre = bdt;
#pragma unroll
    for (int s = 0; s < DS; ++s)
      pre += dtp_lds[j][s] * wdt_lds[s][t];
    const float dtv = fmaxf(pre, 0.f) + log1pf(expf(-fabsf(pre)));  // softplus
    const float xv = bf16_f32(xs[row * DI + d]);
    const float u = dtv * xv;
#pragma unroll
    for (int q = 0; q < 4; ++q) {
      const float4 bq = *(const float4*)&bp_lds[j][q * 4];
      h[q * 4 + 0] += e[q * 4 + 0] * (u * bq.x);
      h[q * 4 + 1] += e[q * 4 + 1] * (u * bq.y);
      h[q * 4 + 2] += e[q * 4 + 2] * (u * bq.z);
      h[q * 4 + 3] += e[q * 4 + 3] * (u * bq.w);
    }
    float hs = 0.f;
#pragma unroll
    for (int s = 0; s < DS; ++s) hs += h[s];
    const float cp = proj[row * NPROJ + 2 * DS + d];
    const float z = bf16_f32(xzb[row * N_XZ + DI + d]);
    const float y = cp * hs + xv * Dd;
    v[row * DI + d] = f32_bf16(y * (z / (1.f + __expf(-z))));
#pragma unroll
    for (int s = 0; s < DS; ++s)
      e[s] *= __expf(dtv * a[s]) + 1e-8f;
  }
}

extern "C" void kernel_launch(void* const* d_in, const int* in_sizes, int n_in,
                              void* d_out, int out_size, void* d_ws, size_t ws_size,
                              hipStream_t stream) {
  const float* x     = (const float*)d_in[0];
  const float* w_in  = (const float*)d_in[1];
  const float* b_in  = (const float*)d_in[2];
  const float* cw    = (const float*)d_in[3];
  const float* cb    = (const float*)d_in[4];
  const float* w_xp  = (const float*)d_in[5];
  const float* b_xp  = (const float*)d_in[6];
  const float* w_dt  = (const float*)d_in[7];
  const float* b_dt  = (const float*)d_in[8];
  const float* Alog  = (const float*)d_in[9];
  const float* Dp    = (const float*)d_in[10];
  const float* w_out = (const float*)d_in[11];
  const float* b_out = (const float*)d_in[12];
  float* out = (float*)d_out;

  // workspace layout, high-water 101,449,728 B (== proven r8/r9/r10 extent).
  // Lifetimes: w1t dead after gemm1 (vb overlays it, written by scanC);
  // xbf dead after gemm1; xzb (bf16) live through scanC (z column);
  // xsb live through scanC; proj live through scanC; Ebuf/Lbuf fresh
  // (written by scanA). Every buffer written before read each call.
  char* ws = (char*)d_ws;
  unsigned short* w1t = (unsigned short*)(ws);              //  8,388,608
  unsigned short* w2t = (unsigned short*)(ws + 8388608);    //  8,912,896
  unsigned short* w3t = (unsigned short*)(ws + 17301504);   //  4,194,304
  unsigned short* xbf = (unsigned short*)(ws + 21495808);   //  4,194,304
  unsigned short* xzb = (unsigned short*)(ws + 25690112);   // 16,777,216 (bf16 xz)
  unsigned short* xsb = (unsigned short*)(ws + 42467328);   //  8,388,608
  float* proj = (float*)(ws + 50855936);                    // 17,039,360 -> 67,895,296
  float* Ebuf = (float*)(ws + 67895296);                    // 16,777,216 -> 84,672,512
  float* Lbuf = (float*)(ws + 84672512);                    // 16,777,216 -> 101,449,728
  unsigned short* vb  = (unsigned short*)(ws);              //  8,388,608 overlay (w1t)

  const dim3 blk(256);
  const dim3 blkg(512);
  // fused prep: 3 transposes + x cast
  k_prep<<<dim3(11520), blk, 0, stream>>>(w_in, w_xp, w_out, x, w1t, w2t, w3t, xbf);
  // xz = x @ in_proj_w + b  (bf16 out)
  k_gemm_bf<1><<<dim3(4096 / 128, 2048 / 128), blkg, 0, stream>>>(xbf, 1024, w1t, 1024, b_in, xzb, 4096, 1024, 4096);
  // xs = silu(causal_dwconv(xc)) [bf16]
  k_conv_silu<<<dim3(NROWS * DI / 256), blk, 0, stream>>>(xzb, cw, cb, xsb);
  // proj = xs @ x_proj_w + b  (f32 out)
  k_gemm_bf<0><<<dim3(NPROJ_PAD / 128, 2048 / 128), blkg, 0, stream>>>(xsb, 2048, w2t, 2048, b_xp, proj, NPROJ, 2048, NPROJ);
  // selective scan (chunk-parallel CH_R=16, dt fused) + gate -> v (bf16)
  k_scanA<<<dim3(TOTCH * 8), blk, 0, stream>>>(proj, xsb, Alog, w_dt, b_dt, Ebuf, Lbuf);
  k_scanB<<<dim3(NB * DI * DS / 256), blk, 0, stream>>>(Ebuf, Lbuf);
  k_scanC<<<dim3(TOTCH * 8), blk, 0, stream>>>(proj, xsb, xzb, Alog, Dp, w_dt, b_dt, Ebuf, Lbuf, vb);
  // out = v @ out_proj_w + b  (f32 out)
  k_gemm_bf<0><<<dim3(1024 / 128, 2048 / 128), blkg, 0, stream>>>(vb, 2048, w3t, 2048, b_out, out, 1024, 2048, 1024);
}